// Round 5
// baseline (349.364 us; speedup 1.0000x reference)
//
#include <hip/hip_runtime.h>
#include <hip/hip_bf16.h>
#include <math.h>

// Problem constants
constexpr int kB     = 4;
constexpr int kH     = 48;
constexpr int kW     = 48;
constexpr int kHW    = 2304;   // 48*48
constexpr int kC     = 256;
constexpr int kHeads = 8;
constexpr int kHD    = 32;
constexpr float kScale = 0.17677669529663687f;  // 32^-0.5

typedef __bf16 bf16x8 __attribute__((ext_vector_type(8)));
typedef float  f32x4  __attribute__((ext_vector_type(4)));
typedef unsigned int   uint32x4 __attribute__((ext_vector_type(4)));
typedef unsigned short ushort8v __attribute__((ext_vector_type(8)));

static __device__ __forceinline__ unsigned short f2bf_bits(float f) {
    return __builtin_bit_cast(unsigned short, __float2bfloat16(f));
}

// ---------------------------------------------------------------------------
// Kernel 1: fused QKV projection GEMM (fp32 compute, LDS-tiled 64x64x16)
// z=0 -> q (RoPE'd, bf16, head-major), z=1 -> k (scaled+RoPE'd, bf16),
// z=2 -> v (fp32, head-major, feeds lepe + transpose).
// ---------------------------------------------------------------------------
__global__ __launch_bounds__(256) void qkv_gemm_kernel(
    const float* __restrict__ x,
    const float* __restrict__ Wq, const float* __restrict__ bq,
    const float* __restrict__ Wk, const float* __restrict__ bk,
    const float* __restrict__ Wv, const float* __restrict__ bv,
    const float* __restrict__ sinb, const float* __restrict__ cosb,
    __hip_bfloat16* __restrict__ qbh, __hip_bfloat16* __restrict__ kbh,
    float* __restrict__ vb)
{
    const int z = blockIdx.z;
    const float* Wt = (z == 0) ? Wq : ((z == 1) ? Wk : Wv);
    const float* bt = (z == 0) ? bq : ((z == 1) ? bk : bv);

    __shared__ __align__(16) float As[16][65];  // [k][m]
    __shared__ __align__(16) float Bs[16][65];  // [k][n]

    const int tid = threadIdx.x;
    const int mBase = blockIdx.x * 64;
    const int nBase = blockIdx.y * 64;

    const int tx = tid & 15;
    const int ty = tid >> 4;

    const int lm  = tid >> 2;
    const int lk  = (tid & 3) * 4;
    const int lbk = tid >> 4;
    const int lbn = (tid & 15) * 4;

    float acc[4][4] = {};

    for (int k0 = 0; k0 < 256; k0 += 16) {
        const float4 av = *reinterpret_cast<const float4*>(
            &x[(size_t)(mBase + lm) * 256 + k0 + lk]);
        As[lk + 0][lm] = av.x; As[lk + 1][lm] = av.y;
        As[lk + 2][lm] = av.z; As[lk + 3][lm] = av.w;

        const float4 bv4 = *reinterpret_cast<const float4*>(
            &Wt[(size_t)(k0 + lbk) * 256 + nBase + lbn]);
        Bs[lbk][lbn + 0] = bv4.x; Bs[lbk][lbn + 1] = bv4.y;
        Bs[lbk][lbn + 2] = bv4.z; Bs[lbk][lbn + 3] = bv4.w;
        __syncthreads();

        #pragma unroll
        for (int kk = 0; kk < 16; ++kk) {
            float a[4], bb[4];
            #pragma unroll
            for (int i = 0; i < 4; ++i) a[i] = As[kk][ty * 4 + i];
            #pragma unroll
            for (int j = 0; j < 4; ++j) bb[j] = Bs[kk][tx * 4 + j];
            #pragma unroll
            for (int i = 0; i < 4; ++i)
                #pragma unroll
                for (int j = 0; j < 4; ++j)
                    acc[i][j] += a[i] * bb[j];
        }
        __syncthreads();
    }

    const int n0   = nBase + tx * 4;
    const int head = n0 >> 5;
    const int d0   = n0 & 31;
    const float scl = (z == 1) ? kScale : 1.0f;

    #pragma unroll
    for (int i = 0; i < 4; ++i) {
        const int m  = mBase + ty * 4 + i;
        const int b  = m / kHW;
        const int hw = m % kHW;
        float t0 = (acc[i][0] + bt[n0 + 0]) * scl;
        float t1 = (acc[i][1] + bt[n0 + 1]) * scl;
        float t2 = (acc[i][2] + bt[n0 + 2]) * scl;
        float t3 = (acc[i][3] + bt[n0 + 3]) * scl;

        if (z == 2) {
            float* vr = vb + (((size_t)(b * kHeads + head) * kHW + hw) << 5) + d0;
            vr[0] = t0; vr[1] = t1; vr[2] = t2; vr[3] = t3;
        } else {
            const float* cs = cosb + hw * 32 + d0;
            const float* sn = sinb + hw * 32 + d0;
            const float r0 = t0 * cs[0] - t1 * sn[0];
            const float r1 = t1 * cs[1] + t0 * sn[1];
            const float r2 = t2 * cs[2] - t3 * sn[2];
            const float r3 = t3 * cs[3] + t2 * sn[3];
            __hip_bfloat16* ob = (z == 0) ? qbh : kbh;
            alignas(8) unsigned short u[4] = {f2bf_bits(r0), f2bf_bits(r1),
                                              f2bf_bits(r2), f2bf_bits(r3)};
            *reinterpret_cast<unsigned long long*>(
                reinterpret_cast<unsigned short*>(ob) +
                (((size_t)(b * kHeads + head) * kHW + hw) << 5) + d0) =
                *reinterpret_cast<unsigned long long*>(u);
        }
    }
}

// ---------------------------------------------------------------------------
// Kernel 2: transpose v (fp32 head-major [bh][hw][32]) -> vt bf16 [bh][32][hw]
// ---------------------------------------------------------------------------
__global__ __launch_bounds__(256) void vt_kernel(
    const float* __restrict__ vb, __hip_bfloat16* __restrict__ vt)
{
    __shared__ float lds[64][33];
    const int bh  = blockIdx.y;
    const int hw0 = blockIdx.x * 64;
    const int t   = threadIdx.x;

    const int hl = t >> 2, dq = (t & 3) * 8;
    const float* src = vb + ((size_t)bh * kHW + hw0 + hl) * 32 + dq;
    const float4 a = *reinterpret_cast<const float4*>(src);
    const float4 b = *reinterpret_cast<const float4*>(src + 4);
    lds[hl][dq + 0] = a.x; lds[hl][dq + 1] = a.y;
    lds[hl][dq + 2] = a.z; lds[hl][dq + 3] = a.w;
    lds[hl][dq + 4] = b.x; lds[hl][dq + 5] = b.y;
    lds[hl][dq + 6] = b.z; lds[hl][dq + 7] = b.w;
    __syncthreads();

    const int d = t >> 3, hq = (t & 7) * 8;
    ushort8v o;
    #pragma unroll
    for (int i = 0; i < 8; ++i) o[i] = f2bf_bits(lds[hq + i][d]);
    *reinterpret_cast<ushort8v*>(
        reinterpret_cast<unsigned short*>(vt) + ((size_t)bh * 32 + d) * kHW + hw0 + hq) = o;
}

// ---------------------------------------------------------------------------
// Kernel 3: LePE 5x5 depthwise conv on v (head-major in, token-major out)
// ---------------------------------------------------------------------------
__global__ __launch_bounds__(256) void lepe_kernel(
    const float* __restrict__ vb,
    const float* __restrict__ lw, const float* __restrict__ lb,
    float* __restrict__ lepe)
{
    const int c   = threadIdx.x;
    const int bhw = blockIdx.x;
    const int b   = bhw / kHW;
    const int hw  = bhw % kHW;
    const int h   = hw / kW;
    const int w   = hw % kW;
    const int head = c >> 5;
    const int d    = c & 31;

    const float* vsrc = vb + ((size_t)(b * kHeads + head) * kHW) * kHD + d;
    float acc = lb[c];
    #pragma unroll
    for (int dh = 0; dh < 5; ++dh) {
        const int h2 = h + dh - 2;
        if (h2 < 0 || h2 >= kH) continue;
        #pragma unroll
        for (int dw = 0; dw < 5; ++dw) {
            const int w2 = w + dw - 2;
            if (w2 < 0 || w2 >= kW) continue;
            acc += vsrc[(size_t)(h2 * kW + w2) * kHD] * lw[(dh * 5 + dw) * kC + c];
        }
    }
    lepe[(size_t)bhw * kC + c] = acc;
}

// ---------------------------------------------------------------------------
// Kernel 4: MFMA attention, k-split for occupancy.
// grid (144 q-tiles of 16 rows, 8 heads, KS k-ranges), block 256 = 4 waves
// (wave = batch, so the 4 waves share identical mask lines; raw s_barrier
// keeps them temporally aligned without draining vmcnt).
// Each block processes kHW/KS keys and emits un-normalized partials
// (po = sum p*v, ls = sum p); exact combine later (no running max is used).
// ---------------------------------------------------------------------------
__global__ __launch_bounds__(256, 4) void attn_mfma_kernel(
    const __hip_bfloat16* __restrict__ qb, const __hip_bfloat16* __restrict__ kb,
    const __hip_bfloat16* __restrict__ vt, const float* __restrict__ mask,
    float* __restrict__ po, float* __restrict__ ls, int kspan)
{
    const int head = blockIdx.y;
    const int ksl  = blockIdx.z;
    const int tid  = threadIdx.x;
    const int wave = tid >> 6;          // = batch b
    const int b    = wave;
    const int bh   = b * kHeads + head;
    const int lane = tid & 63;
    const int lq   = lane & 15;
    const int g    = lane >> 4;
    const int q0   = blockIdx.x * 16;
    const int qrow = q0 + lq;
    const int kt0  = ksl * kspan;

    // Q B-fragment: lane holds Q[qrow][8g .. 8g+7]
    const bf16x8 qfrag = *reinterpret_cast<const bf16x8*>(
        reinterpret_cast<const unsigned short*>(qb) +
        ((size_t)bh * kHW + qrow) * kHD + g * 8);

    const unsigned short* kbase =
        reinterpret_cast<const unsigned short*>(kb) + (size_t)bh * kHW * kHD;
    const unsigned short* v0p =
        reinterpret_cast<const unsigned short*>(vt) + ((size_t)bh * kHD + lq) * kHW;
    const unsigned short* v1p = v0p + (size_t)16 * kHW;
    const float* mrow = mask + ((size_t)head * kHW + qrow) * kHW;

    f32x4 o0 = {0.f, 0.f, 0.f, 0.f};
    f32x4 o1 = {0.f, 0.f, 0.f, 0.f};
    float lsum = 0.f;
    const bool ghi = (g >= 2);

    for (int kt = kt0; kt < kt0 + kspan; kt += 64) {
        // keep the 4 batch-waves in the same kt window so the shared mask
        // lines are L1/L2-served; raw barrier does not drain vmcnt.
        __builtin_amdgcn_s_barrier();

        // K A-fragments (4 j tiles) + mask as MFMA C operand
        bf16x8 kf[4];
        f32x4  mc[4];
        #pragma unroll
        for (int j = 0; j < 4; ++j) {
            kf[j] = *reinterpret_cast<const bf16x8*>(
                kbase + (size_t)(kt + j * 16 + lq) * kHD + g * 8);
            mc[j] = *reinterpret_cast<const f32x4*>(mrow + kt + j * 16 + g * 4);
        }
        // V B-fragments: [h (k-half)][dh (d-half)]
        const bf16x8 va  = *reinterpret_cast<const bf16x8*>(v0p + kt + g * 8);
        const bf16x8 vbf = *reinterpret_cast<const bf16x8*>(v0p + kt + 32 + g * 8);
        const bf16x8 vc  = *reinterpret_cast<const bf16x8*>(v1p + kt + g * 8);
        const bf16x8 vd  = *reinterpret_cast<const bf16x8*>(v1p + kt + 32 + g * 8);

        f32x4 st[4];
        #pragma unroll
        for (int j = 0; j < 4; ++j)
            st[j] = __builtin_amdgcn_mfma_f32_16x16x32_bf16(kf[j], qfrag, mc[j], 0, 0, 0);

        // exp + row-sum partial + pack to bf16 pairs (lane's q = lq)
        unsigned p32[4][2];
        #pragma unroll
        for (int j = 0; j < 4; ++j) {
            const float e0 = __expf(st[j][0]);
            const float e1 = __expf(st[j][1]);
            const float e2 = __expf(st[j][2]);
            const float e3 = __expf(st[j][3]);
            lsum += (e0 + e1) + (e2 + e3);
            p32[j][0] = (unsigned)f2bf_bits(e0) | ((unsigned)f2bf_bits(e1) << 16);
            p32[j][1] = (unsigned)f2bf_bits(e2) | ((unsigned)f2bf_bits(e3) << 16);
        }

        // redistribute P (S^T lane layout) -> PV A-fragment layout.
        unsigned pw0[4], pw1[4];
        #pragma unroll
        for (int t = 0; t < 4; ++t) {
            const int src = lq + 16 * (2 * (g & 1) + (t >> 1));
            const unsigned a0 = __shfl(p32[0][t & 1], src);
            const unsigned a1 = __shfl(p32[1][t & 1], src);
            const unsigned b0 = __shfl(p32[2][t & 1], src);
            const unsigned b1 = __shfl(p32[3][t & 1], src);
            pw0[t] = ghi ? a1 : a0;
            pw1[t] = ghi ? b1 : b0;
        }
        uint32x4 w0 = {pw0[0], pw0[1], pw0[2], pw0[3]};
        uint32x4 w1 = {pw1[0], pw1[1], pw1[2], pw1[3]};
        const bf16x8 pa0 = __builtin_bit_cast(bf16x8, w0);
        const bf16x8 pa1 = __builtin_bit_cast(bf16x8, w1);

        o0 = __builtin_amdgcn_mfma_f32_16x16x32_bf16(pa0, va,  o0, 0, 0, 0);
        o0 = __builtin_amdgcn_mfma_f32_16x16x32_bf16(pa1, vbf, o0, 0, 0, 0);
        o1 = __builtin_amdgcn_mfma_f32_16x16x32_bf16(pa0, vc,  o1, 0, 0, 0);
        o1 = __builtin_amdgcn_mfma_f32_16x16x32_bf16(pa1, vd,  o1, 0, 0, 0);
    }

    // full row-sum for q=lq (partial over this k-range)
    lsum += __shfl_xor(lsum, 16);
    lsum += __shfl_xor(lsum, 32);

    // write un-normalized partials
    const size_t pbase = ((size_t)ksl * (kB * kHeads) + bh) * kHW;
    #pragma unroll
    for (int r = 0; r < 4; ++r) {
        float* orow = po + (pbase + q0 + 4 * g + r) * kHD + lq;
        orow[0]  = o0[r];
        orow[16] = o1[r];
    }
    if (lane < 16) ls[pbase + q0 + lq] = lsum;
}

// ---------------------------------------------------------------------------
// Kernel 4b: combine k-split partials -> normalized attn out (token-major)
// ---------------------------------------------------------------------------
__global__ __launch_bounds__(256) void combine_kernel(
    const float* __restrict__ po, const float* __restrict__ ls,
    float* __restrict__ ao, int ks)
{
    const int idx = blockIdx.x * 256 + threadIdx.x;   // over kB*kHW*kC
    const int c   = idx & 255;
    const int bhw = idx >> 8;
    const int b   = bhw / kHW;
    const int hw  = bhw % kHW;
    const int head = c >> 5;
    const int d    = c & 31;
    const int bh   = b * kHeads + head;

    float o = 0.f, l = 0.f;
    for (int s = 0; s < ks; ++s) {
        const size_t pbase = ((size_t)s * (kB * kHeads) + bh) * kHW + hw;
        o += po[pbase * kHD + d];
        l += ls[pbase];
    }
    ao[(size_t)idx] = o / l;
}

// ---------------------------------------------------------------------------
// Kernel 5: output projection GEMM, fusing (attn_out + lepe) @ Wout + bout
// ---------------------------------------------------------------------------
__global__ __launch_bounds__(256) void out_gemm_kernel(
    const float* __restrict__ a0, const float* __restrict__ a1,
    const float* __restrict__ Wo, const float* __restrict__ bo,
    float* __restrict__ out)
{
    __shared__ __align__(16) float As[16][65];
    __shared__ __align__(16) float Bs[16][65];

    const int tid = threadIdx.x;
    const int mBase = blockIdx.x * 64;
    const int nBase = blockIdx.y * 64;

    const int tx = tid & 15;
    const int ty = tid >> 4;

    const int lm  = tid >> 2;
    const int lk  = (tid & 3) * 4;
    const int lbk = tid >> 4;
    const int lbn = (tid & 15) * 4;

    float acc[4][4] = {};

    for (int k0 = 0; k0 < 256; k0 += 16) {
        const size_t aoff = (size_t)(mBase + lm) * 256 + k0 + lk;
        const float4 av0 = *reinterpret_cast<const float4*>(&a0[aoff]);
        const float4 av1 = *reinterpret_cast<const float4*>(&a1[aoff]);
        As[lk + 0][lm] = av0.x + av1.x; As[lk + 1][lm] = av0.y + av1.y;
        As[lk + 2][lm] = av0.z + av1.z; As[lk + 3][lm] = av0.w + av1.w;

        const float4 bv4 = *reinterpret_cast<const float4*>(
            &Wo[(size_t)(k0 + lbk) * 256 + nBase + lbn]);
        Bs[lbk][lbn + 0] = bv4.x; Bs[lbk][lbn + 1] = bv4.y;
        Bs[lbk][lbn + 2] = bv4.z; Bs[lbk][lbn + 3] = bv4.w;
        __syncthreads();

        #pragma unroll
        for (int kk = 0; kk < 16; ++kk) {
            float a[4], bb[4];
            #pragma unroll
            for (int i = 0; i < 4; ++i) a[i] = As[kk][ty * 4 + i];
            #pragma unroll
            for (int j = 0; j < 4; ++j) bb[j] = Bs[kk][tx * 4 + j];
            #pragma unroll
            for (int i = 0; i < 4; ++i)
                #pragma unroll
                for (int j = 0; j < 4; ++j)
                    acc[i][j] += a[i] * bb[j];
        }
        __syncthreads();
    }

    #pragma unroll
    for (int i = 0; i < 4; ++i) {
        const int m = mBase + ty * 4 + i;
        #pragma unroll
        for (int j = 0; j < 4; ++j) {
            const int n = nBase + tx * 4 + j;
            out[(size_t)m * 256 + n] = acc[i][j] + bo[n];
        }
    }
}

// ---------------------------------------------------------------------------
extern "C" void kernel_launch(void* const* d_in, const int* in_sizes, int n_in,
                              void* d_out, int out_size, void* d_ws, size_t ws_size,
                              hipStream_t stream)
{
    const float* x    = (const float*)d_in[0];
    const float* sinb = (const float*)d_in[1];
    const float* cosb = (const float*)d_in[2];
    const float* mask = (const float*)d_in[3];
    const float* Wq   = (const float*)d_in[4];
    const float* bq   = (const float*)d_in[5];
    const float* Wk   = (const float*)d_in[6];
    const float* bk   = (const float*)d_in[7];
    const float* Wv   = (const float*)d_in[8];
    const float* bv   = (const float*)d_in[9];
    const float* lw   = (const float*)d_in[10];
    const float* lb   = (const float*)d_in[11];
    const float* Wo   = (const float*)d_in[12];
    const float* bo   = (const float*)d_in[13];
    float* out = (float*)d_out;

    const size_t NT = (size_t)kB * kHeads * kHW * kHD;  // 2359296 per tensor
    const size_t fixed = NT * 4 * 3 + NT * 2 * 3;       // vb,lepe,ao + qbh,kbh,vt

    // pick k-split that fits the workspace
    int ks = 4;
    while (ks > 1) {
        const size_t need = fixed + (size_t)ks * (NT * 4 + (size_t)kB * kHeads * kHW * 4);
        if (need <= ws_size) break;
        ks >>= 1;
    }
    const int kspan = kHW / ks;

    char* base = (char*)d_ws;
    float* vb   = (float*)base;             base += NT * 4;
    float* lepe = (float*)base;             base += NT * 4;
    float* ao   = (float*)base;             base += NT * 4;
    __hip_bfloat16* qbh = (__hip_bfloat16*)base; base += NT * 2;
    __hip_bfloat16* kbh = (__hip_bfloat16*)base; base += NT * 2;
    __hip_bfloat16* vt  = (__hip_bfloat16*)base; base += NT * 2;
    float* po = (float*)base;               base += (size_t)ks * NT * 4;
    float* ls = (float*)base;               base += (size_t)ks * kB * kHeads * kHW * 4;

    qkv_gemm_kernel<<<dim3(144, 4, 3), 256, 0, stream>>>(
        x, Wq, bq, Wk, bk, Wv, bv, sinb, cosb, qbh, kbh, vb);
    vt_kernel<<<dim3(36, 32), 256, 0, stream>>>(vb, vt);
    lepe_kernel<<<dim3(9216), 256, 0, stream>>>(vb, lw, lb, lepe);
    attn_mfma_kernel<<<dim3(144, 8, ks), 256, 0, stream>>>(
        qbh, kbh, vt, mask, po, ls, kspan);
    combine_kernel<<<dim3(9216), 256, 0, stream>>>(po, ls, ao, ks);
    out_gemm_kernel<<<dim3(144, 4), 256, 0, stream>>>(ao, lepe, Wo, bo, out);
}

// Round 6
// 300.080 us; speedup vs baseline: 1.1642x; 1.1642x over previous
//
#include <hip/hip_runtime.h>
#include <hip/hip_bf16.h>
#include <math.h>

// Problem constants
constexpr int kB     = 4;
constexpr int kH     = 48;
constexpr int kW     = 48;
constexpr int kHW    = 2304;   // 48*48
constexpr int kC     = 256;
constexpr int kHeads = 8;
constexpr int kHD    = 32;
constexpr float kScale = 0.17677669529663687f;  // 32^-0.5

typedef __bf16 bf16x8 __attribute__((ext_vector_type(8)));
typedef float  f32x4  __attribute__((ext_vector_type(4)));
typedef unsigned int   uint32x4 __attribute__((ext_vector_type(4)));
typedef unsigned short ushort8v __attribute__((ext_vector_type(8)));

static __device__ __forceinline__ unsigned short f2bf_bits(float f) {
    return __builtin_bit_cast(unsigned short, __float2bfloat16(f));
}

// ---------------------------------------------------------------------------
// Kernel 1: fused QKV projection GEMM (fp32 compute, LDS-tiled 64x64x16)
// z=0 -> q (RoPE'd, bf16, head-major), z=1 -> k (scaled+RoPE'd, bf16),
// z=2 -> v (fp32, head-major, feeds lepe + transpose).
// ---------------------------------------------------------------------------
__global__ __launch_bounds__(256) void qkv_gemm_kernel(
    const float* __restrict__ x,
    const float* __restrict__ Wq, const float* __restrict__ bq,
    const float* __restrict__ Wk, const float* __restrict__ bk,
    const float* __restrict__ Wv, const float* __restrict__ bv,
    const float* __restrict__ sinb, const float* __restrict__ cosb,
    __hip_bfloat16* __restrict__ qbh, __hip_bfloat16* __restrict__ kbh,
    float* __restrict__ vb)
{
    const int z = blockIdx.z;
    const float* Wt = (z == 0) ? Wq : ((z == 1) ? Wk : Wv);
    const float* bt = (z == 0) ? bq : ((z == 1) ? bk : bv);

    __shared__ __align__(16) float As[16][65];  // [k][m]
    __shared__ __align__(16) float Bs[16][65];  // [k][n]

    const int tid = threadIdx.x;
    const int mBase = blockIdx.x * 64;
    const int nBase = blockIdx.y * 64;

    const int tx = tid & 15;
    const int ty = tid >> 4;

    const int lm  = tid >> 2;
    const int lk  = (tid & 3) * 4;
    const int lbk = tid >> 4;
    const int lbn = (tid & 15) * 4;

    float acc[4][4] = {};

    for (int k0 = 0; k0 < 256; k0 += 16) {
        const float4 av = *reinterpret_cast<const float4*>(
            &x[(size_t)(mBase + lm) * 256 + k0 + lk]);
        As[lk + 0][lm] = av.x; As[lk + 1][lm] = av.y;
        As[lk + 2][lm] = av.z; As[lk + 3][lm] = av.w;

        const float4 bv4 = *reinterpret_cast<const float4*>(
            &Wt[(size_t)(k0 + lbk) * 256 + nBase + lbn]);
        Bs[lbk][lbn + 0] = bv4.x; Bs[lbk][lbn + 1] = bv4.y;
        Bs[lbk][lbn + 2] = bv4.z; Bs[lbk][lbn + 3] = bv4.w;
        __syncthreads();

        #pragma unroll
        for (int kk = 0; kk < 16; ++kk) {
            float a[4], bb[4];
            #pragma unroll
            for (int i = 0; i < 4; ++i) a[i] = As[kk][ty * 4 + i];
            #pragma unroll
            for (int j = 0; j < 4; ++j) bb[j] = Bs[kk][tx * 4 + j];
            #pragma unroll
            for (int i = 0; i < 4; ++i)
                #pragma unroll
                for (int j = 0; j < 4; ++j)
                    acc[i][j] += a[i] * bb[j];
        }
        __syncthreads();
    }

    const int n0   = nBase + tx * 4;
    const int head = n0 >> 5;
    const int d0   = n0 & 31;
    const float scl = (z == 1) ? kScale : 1.0f;

    #pragma unroll
    for (int i = 0; i < 4; ++i) {
        const int m  = mBase + ty * 4 + i;
        const int b  = m / kHW;
        const int hw = m % kHW;
        float t0 = (acc[i][0] + bt[n0 + 0]) * scl;
        float t1 = (acc[i][1] + bt[n0 + 1]) * scl;
        float t2 = (acc[i][2] + bt[n0 + 2]) * scl;
        float t3 = (acc[i][3] + bt[n0 + 3]) * scl;

        if (z == 2) {
            float* vr = vb + (((size_t)(b * kHeads + head) * kHW + hw) << 5) + d0;
            vr[0] = t0; vr[1] = t1; vr[2] = t2; vr[3] = t3;
        } else {
            const float* cs = cosb + hw * 32 + d0;
            const float* sn = sinb + hw * 32 + d0;
            const float r0 = t0 * cs[0] - t1 * sn[0];
            const float r1 = t1 * cs[1] + t0 * sn[1];
            const float r2 = t2 * cs[2] - t3 * sn[2];
            const float r3 = t3 * cs[3] + t2 * sn[3];
            __hip_bfloat16* ob = (z == 0) ? qbh : kbh;
            alignas(8) unsigned short u[4] = {f2bf_bits(r0), f2bf_bits(r1),
                                              f2bf_bits(r2), f2bf_bits(r3)};
            *reinterpret_cast<unsigned long long*>(
                reinterpret_cast<unsigned short*>(ob) +
                (((size_t)(b * kHeads + head) * kHW + hw) << 5) + d0) =
                *reinterpret_cast<unsigned long long*>(u);
        }
    }
}

// ---------------------------------------------------------------------------
// Kernel 2: transpose v (fp32 head-major [bh][hw][32]) -> vt bf16 [bh][32][hw]
// ---------------------------------------------------------------------------
__global__ __launch_bounds__(256) void vt_kernel(
    const float* __restrict__ vb, __hip_bfloat16* __restrict__ vt)
{
    __shared__ float lds[64][33];
    const int bh  = blockIdx.y;
    const int hw0 = blockIdx.x * 64;
    const int t   = threadIdx.x;

    const int hl = t >> 2, dq = (t & 3) * 8;
    const float* src = vb + ((size_t)bh * kHW + hw0 + hl) * 32 + dq;
    const float4 a = *reinterpret_cast<const float4*>(src);
    const float4 b = *reinterpret_cast<const float4*>(src + 4);
    lds[hl][dq + 0] = a.x; lds[hl][dq + 1] = a.y;
    lds[hl][dq + 2] = a.z; lds[hl][dq + 3] = a.w;
    lds[hl][dq + 4] = b.x; lds[hl][dq + 5] = b.y;
    lds[hl][dq + 6] = b.z; lds[hl][dq + 7] = b.w;
    __syncthreads();

    const int d = t >> 3, hq = (t & 7) * 8;
    ushort8v o;
    #pragma unroll
    for (int i = 0; i < 8; ++i) o[i] = f2bf_bits(lds[hq + i][d]);
    *reinterpret_cast<ushort8v*>(
        reinterpret_cast<unsigned short*>(vt) + ((size_t)bh * 32 + d) * kHW + hw0 + hq) = o;
}

// ---------------------------------------------------------------------------
// Kernel 3: LePE 5x5 depthwise conv on v (head-major in, token-major out)
// ---------------------------------------------------------------------------
__global__ __launch_bounds__(256) void lepe_kernel(
    const float* __restrict__ vb,
    const float* __restrict__ lw, const float* __restrict__ lb,
    float* __restrict__ lepe)
{
    const int c   = threadIdx.x;
    const int bhw = blockIdx.x;
    const int b   = bhw / kHW;
    const int hw  = bhw % kHW;
    const int h   = hw / kW;
    const int w   = hw % kW;
    const int head = c >> 5;
    const int d    = c & 31;

    const float* vsrc = vb + ((size_t)(b * kHeads + head) * kHW) * kHD + d;
    float acc = lb[c];
    #pragma unroll
    for (int dh = 0; dh < 5; ++dh) {
        const int h2 = h + dh - 2;
        if (h2 < 0 || h2 >= kH) continue;
        #pragma unroll
        for (int dw = 0; dw < 5; ++dw) {
            const int w2 = w + dw - 2;
            if (w2 < 0 || w2 >= kW) continue;
            acc += vsrc[(size_t)(h2 * kW + w2) * kHD] * lw[(dh * 5 + dw) * kC + c];
        }
    }
    lepe[(size_t)bhw * kC + c] = acc;
}

// ---------------------------------------------------------------------------
// Kernel 4: MFMA attention, 64-row q-tile per wave (4 sub-tiles of 16) for
// 4x K/V reuse; 4 batch-waves per block share mask lines (raw s_barrier
// keeps them tile-aligned without draining vmcnt). k-split partials.
// Per tile: K frags + V frags loaded ONCE, used by 4 q-sub-tiles.
// ---------------------------------------------------------------------------
__global__ __launch_bounds__(256, 2) void attn_mfma_kernel(
    const __hip_bfloat16* __restrict__ qb, const __hip_bfloat16* __restrict__ kb,
    const __hip_bfloat16* __restrict__ vt, const float* __restrict__ mask,
    float* __restrict__ po, float* __restrict__ ls, int kspan)
{
    const int head = blockIdx.y;
    const int ksl  = blockIdx.z;
    const int tid  = threadIdx.x;
    const int wave = tid >> 6;          // = batch b
    const int b    = wave;
    const int bh   = b * kHeads + head;
    const int lane = tid & 63;
    const int lq   = lane & 15;
    const int g    = lane >> 4;
    const int q0   = blockIdx.x * 64;   // 64 q-rows per block/wave
    const int kt0  = ksl * kspan;

    // Q B-fragments for the 4 q-sub-tiles
    bf16x8 qfrag[4];
    #pragma unroll
    for (int s = 0; s < 4; ++s)
        qfrag[s] = *reinterpret_cast<const bf16x8*>(
            reinterpret_cast<const unsigned short*>(qb) +
            ((size_t)bh * kHW + q0 + 16 * s + lq) * kHD + g * 8);

    const unsigned short* kbase =
        reinterpret_cast<const unsigned short*>(kb) + (size_t)bh * kHW * kHD;
    const unsigned short* v0p =
        reinterpret_cast<const unsigned short*>(vt) + ((size_t)bh * kHD + lq) * kHW;
    const unsigned short* v1p = v0p + (size_t)16 * kHW;

    const float* mrow0 = mask + ((size_t)head * kHW + q0 + lq) * kHW;
    // rows for sub-tile s are mrow0 + 16*s*kHW

    f32x4 o0[4] = {};
    f32x4 o1[4] = {};
    float lsum[4] = {};
    const bool ghi = (g >= 2);

    for (int kt = kt0; kt < kt0 + kspan; kt += 64) {
        // align the 4 batch-waves on the same tile window (mask L1 reuse);
        // raw barrier does not drain vmcnt.
        __builtin_amdgcn_s_barrier();

        // K A-fragments + V B-fragments: loaded once, reused by 4 sub-tiles
        bf16x8 kf[4];
        #pragma unroll
        for (int j = 0; j < 4; ++j)
            kf[j] = *reinterpret_cast<const bf16x8*>(
                kbase + (size_t)(kt + j * 16 + lq) * kHD + g * 8);
        const bf16x8 va  = *reinterpret_cast<const bf16x8*>(v0p + kt + g * 8);
        const bf16x8 vbf = *reinterpret_cast<const bf16x8*>(v0p + kt + 32 + g * 8);
        const bf16x8 vc  = *reinterpret_cast<const bf16x8*>(v1p + kt + g * 8);
        const bf16x8 vd  = *reinterpret_cast<const bf16x8*>(v1p + kt + 32 + g * 8);

        #pragma unroll
        for (int s = 0; s < 4; ++s) {
            const float* mrow = mrow0 + (size_t)(16 * s) * kHW;

            f32x4 st[4];
            #pragma unroll
            for (int j = 0; j < 4; ++j) {
                const f32x4 mc = *reinterpret_cast<const f32x4*>(
                    mrow + kt + j * 16 + g * 4);
                st[j] = __builtin_amdgcn_mfma_f32_16x16x32_bf16(kf[j], qfrag[s], mc, 0, 0, 0);
            }

            // exp + row-sum partial + pack to bf16 pairs (lane's q = lq of sub s)
            unsigned p32[4][2];
            #pragma unroll
            for (int j = 0; j < 4; ++j) {
                const float e0 = __expf(st[j][0]);
                const float e1 = __expf(st[j][1]);
                const float e2 = __expf(st[j][2]);
                const float e3 = __expf(st[j][3]);
                lsum[s] += (e0 + e1) + (e2 + e3);
                p32[j][0] = (unsigned)f2bf_bits(e0) | ((unsigned)f2bf_bits(e1) << 16);
                p32[j][1] = (unsigned)f2bf_bits(e2) | ((unsigned)f2bf_bits(e3) << 16);
            }

            // redistribute P (S^T lane layout) -> PV A-fragment layout
            unsigned pw0[4], pw1[4];
            #pragma unroll
            for (int t = 0; t < 4; ++t) {
                const int src = lq + 16 * (2 * (g & 1) + (t >> 1));
                const unsigned a0 = __shfl(p32[0][t & 1], src);
                const unsigned a1 = __shfl(p32[1][t & 1], src);
                const unsigned b0 = __shfl(p32[2][t & 1], src);
                const unsigned b1 = __shfl(p32[3][t & 1], src);
                pw0[t] = ghi ? a1 : a0;
                pw1[t] = ghi ? b1 : b0;
            }
            uint32x4 w0 = {pw0[0], pw0[1], pw0[2], pw0[3]};
            uint32x4 w1 = {pw1[0], pw1[1], pw1[2], pw1[3]};
            const bf16x8 pa0 = __builtin_bit_cast(bf16x8, w0);
            const bf16x8 pa1 = __builtin_bit_cast(bf16x8, w1);

            o0[s] = __builtin_amdgcn_mfma_f32_16x16x32_bf16(pa0, va,  o0[s], 0, 0, 0);
            o0[s] = __builtin_amdgcn_mfma_f32_16x16x32_bf16(pa1, vbf, o0[s], 0, 0, 0);
            o1[s] = __builtin_amdgcn_mfma_f32_16x16x32_bf16(pa0, vc,  o1[s], 0, 0, 0);
            o1[s] = __builtin_amdgcn_mfma_f32_16x16x32_bf16(pa1, vd,  o1[s], 0, 0, 0);
        }
    }

    // per-sub-tile row-sums + un-normalized partial writes
    const size_t pbase = ((size_t)ksl * (kB * kHeads) + bh) * kHW;
    #pragma unroll
    for (int s = 0; s < 4; ++s) {
        float l = lsum[s];
        l += __shfl_xor(l, 16);
        l += __shfl_xor(l, 32);
        #pragma unroll
        for (int r = 0; r < 4; ++r) {
            float* orow = po + (pbase + q0 + 16 * s + 4 * g + r) * kHD + lq;
            orow[0]  = o0[s][r];
            orow[16] = o1[s][r];
        }
        if (lane < 16) ls[pbase + q0 + 16 * s + lq] = l;
    }
}

// ---------------------------------------------------------------------------
// Kernel 4b: combine k-split partials -> normalized attn out (token-major)
// ---------------------------------------------------------------------------
__global__ __launch_bounds__(256) void combine_kernel(
    const float* __restrict__ po, const float* __restrict__ ls,
    float* __restrict__ ao, int ks)
{
    const int idx = blockIdx.x * 256 + threadIdx.x;   // over kB*kHW*kC
    const int c   = idx & 255;
    const int bhw = idx >> 8;
    const int b   = bhw / kHW;
    const int hw  = bhw % kHW;
    const int head = c >> 5;
    const int d    = c & 31;
    const int bh   = b * kHeads + head;

    float o = 0.f, l = 0.f;
    for (int s = 0; s < ks; ++s) {
        const size_t pbase = ((size_t)s * (kB * kHeads) + bh) * kHW + hw;
        o += po[pbase * kHD + d];
        l += ls[pbase];
    }
    ao[(size_t)idx] = o / l;
}

// ---------------------------------------------------------------------------
// Kernel 5: output projection GEMM, fusing (attn_out + lepe) @ Wout + bout
// ---------------------------------------------------------------------------
__global__ __launch_bounds__(256) void out_gemm_kernel(
    const float* __restrict__ a0, const float* __restrict__ a1,
    const float* __restrict__ Wo, const float* __restrict__ bo,
    float* __restrict__ out)
{
    __shared__ __align__(16) float As[16][65];
    __shared__ __align__(16) float Bs[16][65];

    const int tid = threadIdx.x;
    const int mBase = blockIdx.x * 64;
    const int nBase = blockIdx.y * 64;

    const int tx = tid & 15;
    const int ty = tid >> 4;

    const int lm  = tid >> 2;
    const int lk  = (tid & 3) * 4;
    const int lbk = tid >> 4;
    const int lbn = (tid & 15) * 4;

    float acc[4][4] = {};

    for (int k0 = 0; k0 < 256; k0 += 16) {
        const size_t aoff = (size_t)(mBase + lm) * 256 + k0 + lk;
        const float4 av0 = *reinterpret_cast<const float4*>(&a0[aoff]);
        const float4 av1 = *reinterpret_cast<const float4*>(&a1[aoff]);
        As[lk + 0][lm] = av0.x + av1.x; As[lk + 1][lm] = av0.y + av1.y;
        As[lk + 2][lm] = av0.z + av1.z; As[lk + 3][lm] = av0.w + av1.w;

        const float4 bv4 = *reinterpret_cast<const float4*>(
            &Wo[(size_t)(k0 + lbk) * 256 + nBase + lbn]);
        Bs[lbk][lbn + 0] = bv4.x; Bs[lbk][lbn + 1] = bv4.y;
        Bs[lbk][lbn + 2] = bv4.z; Bs[lbk][lbn + 3] = bv4.w;
        __syncthreads();

        #pragma unroll
        for (int kk = 0; kk < 16; ++kk) {
            float a[4], bb[4];
            #pragma unroll
            for (int i = 0; i < 4; ++i) a[i] = As[kk][ty * 4 + i];
            #pragma unroll
            for (int j = 0; j < 4; ++j) bb[j] = Bs[kk][tx * 4 + j];
            #pragma unroll
            for (int i = 0; i < 4; ++i)
                #pragma unroll
                for (int j = 0; j < 4; ++j)
                    acc[i][j] += a[i] * bb[j];
        }
        __syncthreads();
    }

    #pragma unroll
    for (int i = 0; i < 4; ++i) {
        const int m = mBase + ty * 4 + i;
        #pragma unroll
        for (int j = 0; j < 4; ++j) {
            const int n = nBase + tx * 4 + j;
            out[(size_t)m * 256 + n] = acc[i][j] + bo[n];
        }
    }
}

// ---------------------------------------------------------------------------
extern "C" void kernel_launch(void* const* d_in, const int* in_sizes, int n_in,
                              void* d_out, int out_size, void* d_ws, size_t ws_size,
                              hipStream_t stream)
{
    const float* x    = (const float*)d_in[0];
    const float* sinb = (const float*)d_in[1];
    const float* cosb = (const float*)d_in[2];
    const float* mask = (const float*)d_in[3];
    const float* Wq   = (const float*)d_in[4];
    const float* bq   = (const float*)d_in[5];
    const float* Wk   = (const float*)d_in[6];
    const float* bk   = (const float*)d_in[7];
    const float* Wv   = (const float*)d_in[8];
    const float* bv   = (const float*)d_in[9];
    const float* lw   = (const float*)d_in[10];
    const float* lb   = (const float*)d_in[11];
    const float* Wo   = (const float*)d_in[12];
    const float* bo   = (const float*)d_in[13];
    float* out = (float*)d_out;

    const size_t NT = (size_t)kB * kHeads * kHW * kHD;  // 2359296 per tensor
    const size_t fixed = NT * 4 * 3 + NT * 2 * 3;       // vb,lepe,ao + qbh,kbh,vt

    // pick k-split that fits the workspace
    int ks = 2;
    while (ks > 1) {
        const size_t need = fixed + (size_t)ks * (NT * 4 + (size_t)kB * kHeads * kHW * 4);
        if (need <= ws_size) break;
        ks >>= 1;
    }
    const int kspan = kHW / ks;

    char* base = (char*)d_ws;
    float* vb   = (float*)base;             base += NT * 4;
    float* lepe = (float*)base;             base += NT * 4;
    float* ao   = (float*)base;             base += NT * 4;
    __hip_bfloat16* qbh = (__hip_bfloat16*)base; base += NT * 2;
    __hip_bfloat16* kbh = (__hip_bfloat16*)base; base += NT * 2;
    __hip_bfloat16* vt  = (__hip_bfloat16*)base; base += NT * 2;
    float* po = (float*)base;               base += (size_t)ks * NT * 4;
    float* ls = (float*)base;               base += (size_t)ks * kB * kHeads * kHW * 4;

    qkv_gemm_kernel<<<dim3(144, 4, 3), 256, 0, stream>>>(
        x, Wq, bq, Wk, bk, Wv, bv, sinb, cosb, qbh, kbh, vb);
    vt_kernel<<<dim3(36, 32), 256, 0, stream>>>(vb, vt);
    lepe_kernel<<<dim3(9216), 256, 0, stream>>>(vb, lw, lb, lepe);
    attn_mfma_kernel<<<dim3(36, 8, ks), 256, 0, stream>>>(
        qbh, kbh, vt, mask, po, ls, kspan);
    combine_kernel<<<dim3(9216), 256, 0, stream>>>(po, ls, ao, ks);
    out_gemm_kernel<<<dim3(144, 4), 256, 0, stream>>>(ao, lepe, Wo, bo, out);
}

// Round 7
// 284.871 us; speedup vs baseline: 1.2264x; 1.0534x over previous
//
#include <hip/hip_runtime.h>
#include <hip/hip_bf16.h>
#include <math.h>

// Problem constants
constexpr int kB     = 4;
constexpr int kH     = 48;
constexpr int kW     = 48;
constexpr int kHW    = 2304;   // 48*48
constexpr int kC     = 256;
constexpr int kHeads = 8;
constexpr int kHD    = 32;
constexpr float kScale = 0.17677669529663687f;  // 32^-0.5

typedef __bf16 bf16x8 __attribute__((ext_vector_type(8)));
typedef float  f32x4  __attribute__((ext_vector_type(4)));
typedef unsigned int   uint32x4 __attribute__((ext_vector_type(4)));
typedef unsigned short ushort8v __attribute__((ext_vector_type(8)));

static __device__ __forceinline__ unsigned short f2bf_bits(float f) {
    return __builtin_bit_cast(unsigned short, __float2bfloat16(f));
}

// async global->LDS, 16B per lane; LDS dest = wave-uniform base + lane*16
static __device__ __forceinline__ void gll16(const void* g, void* l) {
    __builtin_amdgcn_global_load_lds(
        (const __attribute__((address_space(1))) void*)g,
        (__attribute__((address_space(3))) void*)l, 16, 0, 0);
}

// ---------------------------------------------------------------------------
// Kernel 1: fused QKV projection GEMM (fp32 compute, LDS-tiled 64x64x16)
// z=0 -> q (RoPE'd, bf16, head-major), z=1 -> k (scaled+RoPE'd, bf16),
// z=2 -> v (fp32, head-major, feeds lepe + transpose).
// ---------------------------------------------------------------------------
__global__ __launch_bounds__(256) void qkv_gemm_kernel(
    const float* __restrict__ x,
    const float* __restrict__ Wq, const float* __restrict__ bq,
    const float* __restrict__ Wk, const float* __restrict__ bk,
    const float* __restrict__ Wv, const float* __restrict__ bv,
    const float* __restrict__ sinb, const float* __restrict__ cosb,
    __hip_bfloat16* __restrict__ qbh, __hip_bfloat16* __restrict__ kbh,
    float* __restrict__ vb)
{
    const int z = blockIdx.z;
    const float* Wt = (z == 0) ? Wq : ((z == 1) ? Wk : Wv);
    const float* bt = (z == 0) ? bq : ((z == 1) ? bk : bv);

    __shared__ __align__(16) float As[16][65];  // [k][m]
    __shared__ __align__(16) float Bs[16][65];  // [k][n]

    const int tid = threadIdx.x;
    const int mBase = blockIdx.x * 64;
    const int nBase = blockIdx.y * 64;

    const int tx = tid & 15;
    const int ty = tid >> 4;

    const int lm  = tid >> 2;
    const int lk  = (tid & 3) * 4;
    const int lbk = tid >> 4;
    const int lbn = (tid & 15) * 4;

    float acc[4][4] = {};

    for (int k0 = 0; k0 < 256; k0 += 16) {
        const float4 av = *reinterpret_cast<const float4*>(
            &x[(size_t)(mBase + lm) * 256 + k0 + lk]);
        As[lk + 0][lm] = av.x; As[lk + 1][lm] = av.y;
        As[lk + 2][lm] = av.z; As[lk + 3][lm] = av.w;

        const float4 bv4 = *reinterpret_cast<const float4*>(
            &Wt[(size_t)(k0 + lbk) * 256 + nBase + lbn]);
        Bs[lbk][lbn + 0] = bv4.x; Bs[lbk][lbn + 1] = bv4.y;
        Bs[lbk][lbn + 2] = bv4.z; Bs[lbk][lbn + 3] = bv4.w;
        __syncthreads();

        #pragma unroll
        for (int kk = 0; kk < 16; ++kk) {
            float a[4], bb[4];
            #pragma unroll
            for (int i = 0; i < 4; ++i) a[i] = As[kk][ty * 4 + i];
            #pragma unroll
            for (int j = 0; j < 4; ++j) bb[j] = Bs[kk][tx * 4 + j];
            #pragma unroll
            for (int i = 0; i < 4; ++i)
                #pragma unroll
                for (int j = 0; j < 4; ++j)
                    acc[i][j] += a[i] * bb[j];
        }
        __syncthreads();
    }

    const int n0   = nBase + tx * 4;
    const int head = n0 >> 5;
    const int d0   = n0 & 31;
    const float scl = (z == 1) ? kScale : 1.0f;

    #pragma unroll
    for (int i = 0; i < 4; ++i) {
        const int m  = mBase + ty * 4 + i;
        const int b  = m / kHW;
        const int hw = m % kHW;
        float t0 = (acc[i][0] + bt[n0 + 0]) * scl;
        float t1 = (acc[i][1] + bt[n0 + 1]) * scl;
        float t2 = (acc[i][2] + bt[n0 + 2]) * scl;
        float t3 = (acc[i][3] + bt[n0 + 3]) * scl;

        if (z == 2) {
            float* vr = vb + (((size_t)(b * kHeads + head) * kHW + hw) << 5) + d0;
            vr[0] = t0; vr[1] = t1; vr[2] = t2; vr[3] = t3;
        } else {
            const float* cs = cosb + hw * 32 + d0;
            const float* sn = sinb + hw * 32 + d0;
            const float r0 = t0 * cs[0] - t1 * sn[0];
            const float r1 = t1 * cs[1] + t0 * sn[1];
            const float r2 = t2 * cs[2] - t3 * sn[2];
            const float r3 = t3 * cs[3] + t2 * sn[3];
            __hip_bfloat16* ob = (z == 0) ? qbh : kbh;
            alignas(8) unsigned short u[4] = {f2bf_bits(r0), f2bf_bits(r1),
                                              f2bf_bits(r2), f2bf_bits(r3)};
            *reinterpret_cast<unsigned long long*>(
                reinterpret_cast<unsigned short*>(ob) +
                (((size_t)(b * kHeads + head) * kHW + hw) << 5) + d0) =
                *reinterpret_cast<unsigned long long*>(u);
        }
    }
}

// ---------------------------------------------------------------------------
// Kernel 2: transpose v (fp32 head-major [bh][hw][32]) -> vt bf16 [bh][32][hw]
// ---------------------------------------------------------------------------
__global__ __launch_bounds__(256) void vt_kernel(
    const float* __restrict__ vb, __hip_bfloat16* __restrict__ vt)
{
    __shared__ float lds[64][33];
    const int bh  = blockIdx.y;
    const int hw0 = blockIdx.x * 64;
    const int t   = threadIdx.x;

    const int hl = t >> 2, dq = (t & 3) * 8;
    const float* src = vb + ((size_t)bh * kHW + hw0 + hl) * 32 + dq;
    const float4 a = *reinterpret_cast<const float4*>(src);
    const float4 b = *reinterpret_cast<const float4*>(src + 4);
    lds[hl][dq + 0] = a.x; lds[hl][dq + 1] = a.y;
    lds[hl][dq + 2] = a.z; lds[hl][dq + 3] = a.w;
    lds[hl][dq + 4] = b.x; lds[hl][dq + 5] = b.y;
    lds[hl][dq + 6] = b.z; lds[hl][dq + 7] = b.w;
    __syncthreads();

    const int d = t >> 3, hq = (t & 7) * 8;
    ushort8v o;
    #pragma unroll
    for (int i = 0; i < 8; ++i) o[i] = f2bf_bits(lds[hq + i][d]);
    *reinterpret_cast<ushort8v*>(
        reinterpret_cast<unsigned short*>(vt) + ((size_t)bh * 32 + d) * kHW + hw0 + hq) = o;
}

// ---------------------------------------------------------------------------
// Kernel 3: LePE 5x5 depthwise conv on v (head-major in, token-major out)
// ---------------------------------------------------------------------------
__global__ __launch_bounds__(256) void lepe_kernel(
    const float* __restrict__ vb,
    const float* __restrict__ lw, const float* __restrict__ lb,
    float* __restrict__ lepe)
{
    const int c   = threadIdx.x;
    const int bhw = blockIdx.x;
    const int b   = bhw / kHW;
    const int hw  = bhw % kHW;
    const int h   = hw / kW;
    const int w   = hw % kW;
    const int head = c >> 5;
    const int d    = c & 31;

    const float* vsrc = vb + ((size_t)(b * kHeads + head) * kHW) * kHD + d;
    float acc = lb[c];
    #pragma unroll
    for (int dh = 0; dh < 5; ++dh) {
        const int h2 = h + dh - 2;
        if (h2 < 0 || h2 >= kH) continue;
        #pragma unroll
        for (int dw = 0; dw < 5; ++dw) {
            const int w2 = w + dw - 2;
            if (w2 < 0 || w2 >= kW) continue;
            acc += vsrc[(size_t)(h2 * kW + w2) * kHD] * lw[(dh * 5 + dw) * kC + c];
        }
    }
    lepe[(size_t)bhw * kC + c] = acc;
}

// ---------------------------------------------------------------------------
// Kernel 4: MFMA attention, LDS-staged via global_load_lds (dbuf + counted
// vmcnt). Block = (64 q-rows, head, k-range); 4 waves = 4 batches.
// Per 64-key tile: mask[64][64]f32 (shared, 16KB) + per-batch K[64][32]bf16
// (4KB) + V[32][64]bf16 (4KB) staged contiguously with pre-swizzled sources
// (XOR swizzle -> bank-balanced ds_read_b128 fragment reads). 12 glls/wave.
// Schedule: STAGE(t+1); vmcnt(12); barrier; COMPUTE(t); lgkmcnt(0); barrier.
// ---------------------------------------------------------------------------
__global__ __launch_bounds__(256, 1) void attn_mfma_kernel(
    const __hip_bfloat16* __restrict__ qb, const __hip_bfloat16* __restrict__ kb,
    const __hip_bfloat16* __restrict__ vt, const float* __restrict__ mask,
    float* __restrict__ po, float* __restrict__ ls, int kspan)
{
    extern __shared__ __align__(16) char smem[];   // 2 x (16K mask + 16K K + 16K V)
    constexpr int kBufStride = 49152;
    constexpr int kKOff = 16384;
    constexpr int kVOff = 32768;

    const int head = blockIdx.y;
    const int ksl  = blockIdx.z;
    const int tid  = threadIdx.x;
    const int w    = tid >> 6;          // wave = batch b
    const int bh   = w * kHeads + head;
    const int lane = tid & 63;
    const int lq   = lane & 15;
    const int g    = lane >> 4;
    const int q0   = blockIdx.x * 64;
    const int kt0  = ksl * kspan;
    const int nt   = kspan >> 6;

    // Q B-fragments for the 4 q-sub-tiles
    bf16x8 qfrag[4];
    #pragma unroll
    for (int s = 0; s < 4; ++s)
        qfrag[s] = *reinterpret_cast<const bf16x8*>(
            reinterpret_cast<const unsigned short*>(qb) +
            ((size_t)bh * kHW + q0 + 16 * s + lq) * kHD + g * 8);

    // per-lane pre-swizzled gll source pointers.
    // invariants: mask[row][cb] at LDS unit row*16 + (cb^(row&7));
    //             K[key][slot]  at unit key*4 + (slot^(key&3));
    //             V[d][cu]      at unit d*8 + (cu^(d&7)).   (unit = 16B)
    const float* msrc[4];
    const unsigned short* ksrc[4];
    const unsigned short* vsrc[4];
    {
        const unsigned short* kb_bh =
            reinterpret_cast<const unsigned short*>(kb) + (size_t)bh * kHW * kHD;
        const unsigned short* vt_bh =
            reinterpret_cast<const unsigned short*>(vt) + (size_t)bh * kHD * kHW;
        #pragma unroll
        for (int i = 0; i < 4; ++i) {
            const int mrow = w * 16 + i * 4 + (lane >> 4);
            const int mcb  = (lane & 15) ^ (mrow & 7);
            msrc[i] = mask + ((size_t)head * kHW + q0 + mrow) * kHW + kt0 + mcb * 4;
            const int key   = i * 16 + (lane >> 2);
            const int kslot = (lane & 3) ^ (key & 3);
            ksrc[i] = kb_bh + (size_t)(kt0 + key) * kHD + kslot * 8;
            const int d   = i * 8 + (lane >> 3);
            const int vcu = (lane & 7) ^ (d & 7);
            vsrc[i] = vt_bh + (size_t)d * kHW + kt0 + vcu * 8;
        }
    }

    auto STAGE = [&](int bufo, int tt) {
        char* mb  = smem + bufo;
        char* kbf = smem + bufo + kKOff + w * 4096;
        char* vbf = smem + bufo + kVOff + w * 4096;
        #pragma unroll
        for (int i = 0; i < 4; ++i) {
            gll16(msrc[i] + tt * 64,      mb  + (w * 16 + i * 4) * 256);
            gll16(ksrc[i] + tt * 64 * 32, kbf + i * 1024);
            gll16(vsrc[i] + tt * 64,      vbf + i * 1024);
        }
    };

    f32x4 o0[4] = {};
    f32x4 o1[4] = {};
    float lsum[4] = {};
    const bool ghi = (g >= 2);

    // fragment read offsets (swizzled)
    const int koff = lq * 64 + ((g ^ (lq & 3)) * 16);
    const int vxa  = (g ^ (lq & 7)) * 16;
    const int vxb  = ((4 + g) ^ (lq & 7)) * 16;

    STAGE(0, 0);

    int cur = 0;
    for (int t = 0; t < nt; ++t) {
        if (t + 1 < nt) {
            STAGE(cur ^ kBufStride, t + 1);
            asm volatile("s_waitcnt vmcnt(12)" ::: "memory");
        } else {
            asm volatile("s_waitcnt vmcnt(0)" ::: "memory");
        }
        __builtin_amdgcn_s_barrier();
        __builtin_amdgcn_sched_barrier(0);

        const char* mb  = smem + cur;
        const char* kbf = smem + cur + kKOff + w * 4096;
        const char* vbf = smem + cur + kVOff + w * 4096;

        bf16x8 kf[4];
        #pragma unroll
        for (int j = 0; j < 4; ++j)
            kf[j] = *reinterpret_cast<const bf16x8*>(kbf + j * 1024 + koff);
        const bf16x8 va  = *reinterpret_cast<const bf16x8*>(vbf + lq * 128 + vxa);
        const bf16x8 vb2 = *reinterpret_cast<const bf16x8*>(vbf + lq * 128 + vxb);
        const bf16x8 vc  = *reinterpret_cast<const bf16x8*>(vbf + (16 + lq) * 128 + vxa);
        const bf16x8 vd  = *reinterpret_cast<const bf16x8*>(vbf + (16 + lq) * 128 + vxb);

        #pragma unroll
        for (int s = 0; s < 4; ++s) {
            f32x4 st[4];
            #pragma unroll
            for (int j = 0; j < 4; ++j) {
                const f32x4 mc = *reinterpret_cast<const f32x4*>(
                    mb + s * 4096 + lq * 256 + (((4 * j + g) ^ (lq & 7)) * 16));
                st[j] = __builtin_amdgcn_mfma_f32_16x16x32_bf16(kf[j], qfrag[s], mc, 0, 0, 0);
            }

            unsigned p32[4][2];
            #pragma unroll
            for (int j = 0; j < 4; ++j) {
                const float e0 = __expf(st[j][0]);
                const float e1 = __expf(st[j][1]);
                const float e2 = __expf(st[j][2]);
                const float e3 = __expf(st[j][3]);
                lsum[s] += (e0 + e1) + (e2 + e3);
                p32[j][0] = (unsigned)f2bf_bits(e0) | ((unsigned)f2bf_bits(e1) << 16);
                p32[j][1] = (unsigned)f2bf_bits(e2) | ((unsigned)f2bf_bits(e3) << 16);
            }

            unsigned pw0[4], pw1[4];
            #pragma unroll
            for (int t2 = 0; t2 < 4; ++t2) {
                const int src = lq + 16 * (2 * (g & 1) + (t2 >> 1));
                const unsigned a0 = __shfl(p32[0][t2 & 1], src);
                const unsigned a1 = __shfl(p32[1][t2 & 1], src);
                const unsigned b0 = __shfl(p32[2][t2 & 1], src);
                const unsigned b1 = __shfl(p32[3][t2 & 1], src);
                pw0[t2] = ghi ? a1 : a0;
                pw1[t2] = ghi ? b1 : b0;
            }
            uint32x4 w0 = {pw0[0], pw0[1], pw0[2], pw0[3]};
            uint32x4 w1 = {pw1[0], pw1[1], pw1[2], pw1[3]};
            const bf16x8 pa0 = __builtin_bit_cast(bf16x8, w0);
            const bf16x8 pa1 = __builtin_bit_cast(bf16x8, w1);

            o0[s] = __builtin_amdgcn_mfma_f32_16x16x32_bf16(pa0, va,  o0[s], 0, 0, 0);
            o0[s] = __builtin_amdgcn_mfma_f32_16x16x32_bf16(pa1, vb2, o0[s], 0, 0, 0);
            o1[s] = __builtin_amdgcn_mfma_f32_16x16x32_bf16(pa0, vc,  o1[s], 0, 0, 0);
            o1[s] = __builtin_amdgcn_mfma_f32_16x16x32_bf16(pa1, vd,  o1[s], 0, 0, 0);
        }

        asm volatile("s_waitcnt lgkmcnt(0)" ::: "memory");
        __builtin_amdgcn_s_barrier();
        cur ^= kBufStride;
    }

    // per-sub-tile row-sums + un-normalized partial writes
    const size_t pbase = ((size_t)ksl * (kB * kHeads) + bh) * kHW;
    #pragma unroll
    for (int s = 0; s < 4; ++s) {
        float l = lsum[s];
        l += __shfl_xor(l, 16);
        l += __shfl_xor(l, 32);
        #pragma unroll
        for (int r = 0; r < 4; ++r) {
            float* orow = po + (pbase + q0 + 16 * s + 4 * g + r) * kHD + lq;
            orow[0]  = o0[s][r];
            orow[16] = o1[s][r];
        }
        if (lane < 16) ls[pbase + q0 + 16 * s + lq] = l;
    }
}

// ---------------------------------------------------------------------------
// Kernel 4b: combine k-split partials -> normalized attn out (token-major)
// ---------------------------------------------------------------------------
__global__ __launch_bounds__(256) void combine_kernel(
    const float* __restrict__ po, const float* __restrict__ ls,
    float* __restrict__ ao, int ks)
{
    const int idx = blockIdx.x * 256 + threadIdx.x;   // over kB*kHW*kC
    const int c   = idx & 255;
    const int bhw = idx >> 8;
    const int b   = bhw / kHW;
    const int hw  = bhw % kHW;
    const int head = c >> 5;
    const int d    = c & 31;
    const int bh   = b * kHeads + head;

    float o = 0.f, l = 0.f;
    for (int s = 0; s < ks; ++s) {
        const size_t pbase = ((size_t)s * (kB * kHeads) + bh) * kHW + hw;
        o += po[pbase * kHD + d];
        l += ls[pbase];
    }
    ao[(size_t)idx] = o / l;
}

// ---------------------------------------------------------------------------
// Kernel 5: output projection GEMM, fusing (attn_out + lepe) @ Wout + bout
// ---------------------------------------------------------------------------
__global__ __launch_bounds__(256) void out_gemm_kernel(
    const float* __restrict__ a0, const float* __restrict__ a1,
    const float* __restrict__ Wo, const float* __restrict__ bo,
    float* __restrict__ out)
{
    __shared__ __align__(16) float As[16][65];
    __shared__ __align__(16) float Bs[16][65];

    const int tid = threadIdx.x;
    const int mBase = blockIdx.x * 64;
    const int nBase = blockIdx.y * 64;

    const int tx = tid & 15;
    const int ty = tid >> 4;

    const int lm  = tid >> 2;
    const int lk  = (tid & 3) * 4;
    const int lbk = tid >> 4;
    const int lbn = (tid & 15) * 4;

    float acc[4][4] = {};

    for (int k0 = 0; k0 < 256; k0 += 16) {
        const size_t aoff = (size_t)(mBase + lm) * 256 + k0 + lk;
        const float4 av0 = *reinterpret_cast<const float4*>(&a0[aoff]);
        const float4 av1 = *reinterpret_cast<const float4*>(&a1[aoff]);
        As[lk + 0][lm] = av0.x + av1.x; As[lk + 1][lm] = av0.y + av1.y;
        As[lk + 2][lm] = av0.z + av1.z; As[lk + 3][lm] = av0.w + av1.w;

        const float4 bv4 = *reinterpret_cast<const float4*>(
            &Wo[(size_t)(k0 + lbk) * 256 + nBase + lbn]);
        Bs[lbk][lbn + 0] = bv4.x; Bs[lbk][lbn + 1] = bv4.y;
        Bs[lbk][lbn + 2] = bv4.z; Bs[lbk][lbn + 3] = bv4.w;
        __syncthreads();

        #pragma unroll
        for (int kk = 0; kk < 16; ++kk) {
            float a[4], bb[4];
            #pragma unroll
            for (int i = 0; i < 4; ++i) a[i] = As[kk][ty * 4 + i];
            #pragma unroll
            for (int j = 0; j < 4; ++j) bb[j] = Bs[kk][tx * 4 + j];
            #pragma unroll
            for (int i = 0; i < 4; ++i)
                #pragma unroll
                for (int j = 0; j < 4; ++j)
                    acc[i][j] += a[i] * bb[j];
        }
        __syncthreads();
    }

    #pragma unroll
    for (int i = 0; i < 4; ++i) {
        const int m = mBase + ty * 4 + i;
        #pragma unroll
        for (int j = 0; j < 4; ++j) {
            const int n = nBase + tx * 4 + j;
            out[(size_t)m * 256 + n] = acc[i][j] + bo[n];
        }
    }
}

// ---------------------------------------------------------------------------
extern "C" void kernel_launch(void* const* d_in, const int* in_sizes, int n_in,
                              void* d_out, int out_size, void* d_ws, size_t ws_size,
                              hipStream_t stream)
{
    const float* x    = (const float*)d_in[0];
    const float* sinb = (const float*)d_in[1];
    const float* cosb = (const float*)d_in[2];
    const float* mask = (const float*)d_in[3];
    const float* Wq   = (const float*)d_in[4];
    const float* bq   = (const float*)d_in[5];
    const float* Wk   = (const float*)d_in[6];
    const float* bk   = (const float*)d_in[7];
    const float* Wv   = (const float*)d_in[8];
    const float* bv   = (const float*)d_in[9];
    const float* lw   = (const float*)d_in[10];
    const float* lb   = (const float*)d_in[11];
    const float* Wo   = (const float*)d_in[12];
    const float* bo   = (const float*)d_in[13];
    float* out = (float*)d_out;

    const size_t NT = (size_t)kB * kHeads * kHW * kHD;  // 2359296 per tensor
    const size_t fixed = NT * 4 * 3 + NT * 2 * 3;       // vb,lepe,ao + qbh,kbh,vt

    // pick k-split that fits the workspace
    int ks = 4;
    while (ks > 1) {
        const size_t need = fixed + (size_t)ks * (NT * 4 + (size_t)kB * kHeads * kHW * 4);
        if (need <= ws_size) break;
        ks >>= 1;
    }
    const int kspan = kHW / ks;

    char* base = (char*)d_ws;
    float* vb   = (float*)base;             base += NT * 4;
    float* lepe = (float*)base;             base += NT * 4;
    float* ao   = (float*)base;             base += NT * 4;
    __hip_bfloat16* qbh = (__hip_bfloat16*)base; base += NT * 2;
    __hip_bfloat16* kbh = (__hip_bfloat16*)base; base += NT * 2;
    __hip_bfloat16* vt  = (__hip_bfloat16*)base; base += NT * 2;
    float* po = (float*)base;               base += (size_t)ks * NT * 4;
    float* ls = (float*)base;               base += (size_t)ks * kB * kHeads * kHW * 4;

    qkv_gemm_kernel<<<dim3(144, 4, 3), 256, 0, stream>>>(
        x, Wq, bq, Wk, bk, Wv, bv, sinb, cosb, qbh, kbh, vb);
    vt_kernel<<<dim3(36, 32), 256, 0, stream>>>(vb, vt);
    lepe_kernel<<<dim3(9216), 256, 0, stream>>>(vb, lw, lb, lepe);
    attn_mfma_kernel<<<dim3(36, 8, ks), 256, 98304, stream>>>(
        qbh, kbh, vt, mask, po, ls, kspan);
    combine_kernel<<<dim3(9216), 256, 0, stream>>>(po, ls, ao, ks);
    out_gemm_kernel<<<dim3(144, 4), 256, 0, stream>>>(ao, lepe, Wo, bo, out);
}

// Round 8
// 259.570 us; speedup vs baseline: 1.3459x; 1.0975x over previous
//
#include <hip/hip_runtime.h>
#include <hip/hip_bf16.h>
#include <math.h>

// Problem constants
constexpr int kB     = 4;
constexpr int kH     = 48;
constexpr int kW     = 48;
constexpr int kHW    = 2304;   // 48*48
constexpr int kC     = 256;
constexpr int kHeads = 8;
constexpr int kHD    = 32;
constexpr float kScale = 0.17677669529663687f;  // 32^-0.5

typedef __bf16 bf16x8 __attribute__((ext_vector_type(8)));
typedef float  f32x4  __attribute__((ext_vector_type(4)));
typedef unsigned int   uint32x4 __attribute__((ext_vector_type(4)));
typedef unsigned short ushort8v __attribute__((ext_vector_type(8)));

static __device__ __forceinline__ unsigned short f2bf_bits(float f) {
    return __builtin_bit_cast(unsigned short, __float2bfloat16(f));
}

// packed f32x2 -> bf16x2 in one instruction (T12 primitive; no builtin on gfx950)
static __device__ __forceinline__ unsigned cvt_pk_bf16(float lo, float hi) {
    unsigned r;
    asm("v_cvt_pk_bf16_f32 %0, %1, %2" : "=v"(r) : "v"(lo), "v"(hi));
    return r;
}

// async global->LDS, 16B per lane; LDS dest = wave-uniform base + lane*16
static __device__ __forceinline__ void gll16(const void* g, void* l) {
    __builtin_amdgcn_global_load_lds(
        (const __attribute__((address_space(1))) void*)g,
        (__attribute__((address_space(3))) void*)l, 16, 0, 0);
}

// ---------------------------------------------------------------------------
// Kernel 1: fused QKV projection GEMM (fp32 compute, LDS-tiled 64x64x16)
// z=0 -> q (RoPE'd, bf16, head-major), z=1 -> k (scaled+RoPE'd, bf16),
// z=2 -> v (fp32, head-major, feeds lepe + transpose).
// ---------------------------------------------------------------------------
__global__ __launch_bounds__(256) void qkv_gemm_kernel(
    const float* __restrict__ x,
    const float* __restrict__ Wq, const float* __restrict__ bq,
    const float* __restrict__ Wk, const float* __restrict__ bk,
    const float* __restrict__ Wv, const float* __restrict__ bv,
    const float* __restrict__ sinb, const float* __restrict__ cosb,
    __hip_bfloat16* __restrict__ qbh, __hip_bfloat16* __restrict__ kbh,
    float* __restrict__ vb)
{
    const int z = blockIdx.z;
    const float* Wt = (z == 0) ? Wq : ((z == 1) ? Wk : Wv);
    const float* bt = (z == 0) ? bq : ((z == 1) ? bk : bv);

    __shared__ __align__(16) float As[16][65];  // [k][m]
    __shared__ __align__(16) float Bs[16][65];  // [k][n]

    const int tid = threadIdx.x;
    const int mBase = blockIdx.x * 64;
    const int nBase = blockIdx.y * 64;

    const int tx = tid & 15;
    const int ty = tid >> 4;

    const int lm  = tid >> 2;
    const int lk  = (tid & 3) * 4;
    const int lbk = tid >> 4;
    const int lbn = (tid & 15) * 4;

    float acc[4][4] = {};

    for (int k0 = 0; k0 < 256; k0 += 16) {
        const float4 av = *reinterpret_cast<const float4*>(
            &x[(size_t)(mBase + lm) * 256 + k0 + lk]);
        As[lk + 0][lm] = av.x; As[lk + 1][lm] = av.y;
        As[lk + 2][lm] = av.z; As[lk + 3][lm] = av.w;

        const float4 bv4 = *reinterpret_cast<const float4*>(
            &Wt[(size_t)(k0 + lbk) * 256 + nBase + lbn]);
        Bs[lbk][lbn + 0] = bv4.x; Bs[lbk][lbn + 1] = bv4.y;
        Bs[lbk][lbn + 2] = bv4.z; Bs[lbk][lbn + 3] = bv4.w;
        __syncthreads();

        #pragma unroll
        for (int kk = 0; kk < 16; ++kk) {
            float a[4], bb[4];
            #pragma unroll
            for (int i = 0; i < 4; ++i) a[i] = As[kk][ty * 4 + i];
            #pragma unroll
            for (int j = 0; j < 4; ++j) bb[j] = Bs[kk][tx * 4 + j];
            #pragma unroll
            for (int i = 0; i < 4; ++i)
                #pragma unroll
                for (int j = 0; j < 4; ++j)
                    acc[i][j] += a[i] * bb[j];
        }
        __syncthreads();
    }

    const int n0   = nBase + tx * 4;
    const int head = n0 >> 5;
    const int d0   = n0 & 31;
    const float scl = (z == 1) ? kScale : 1.0f;

    #pragma unroll
    for (int i = 0; i < 4; ++i) {
        const int m  = mBase + ty * 4 + i;
        const int b  = m / kHW;
        const int hw = m % kHW;
        float t0 = (acc[i][0] + bt[n0 + 0]) * scl;
        float t1 = (acc[i][1] + bt[n0 + 1]) * scl;
        float t2 = (acc[i][2] + bt[n0 + 2]) * scl;
        float t3 = (acc[i][3] + bt[n0 + 3]) * scl;

        if (z == 2) {
            float* vr = vb + (((size_t)(b * kHeads + head) * kHW + hw) << 5) + d0;
            vr[0] = t0; vr[1] = t1; vr[2] = t2; vr[3] = t3;
        } else {
            const float* cs = cosb + hw * 32 + d0;
            const float* sn = sinb + hw * 32 + d0;
            const float r0 = t0 * cs[0] - t1 * sn[0];
            const float r1 = t1 * cs[1] + t0 * sn[1];
            const float r2 = t2 * cs[2] - t3 * sn[2];
            const float r3 = t3 * cs[3] + t2 * sn[3];
            __hip_bfloat16* ob = (z == 0) ? qbh : kbh;
            alignas(8) unsigned short u[4] = {f2bf_bits(r0), f2bf_bits(r1),
                                              f2bf_bits(r2), f2bf_bits(r3)};
            *reinterpret_cast<unsigned long long*>(
                reinterpret_cast<unsigned short*>(ob) +
                (((size_t)(b * kHeads + head) * kHW + hw) << 5) + d0) =
                *reinterpret_cast<unsigned long long*>(u);
        }
    }
}

// ---------------------------------------------------------------------------
// Kernel 2: transpose v (fp32 head-major [bh][hw][32]) -> vt bf16 [bh][32][hw]
// ---------------------------------------------------------------------------
__global__ __launch_bounds__(256) void vt_kernel(
    const float* __restrict__ vb, __hip_bfloat16* __restrict__ vt)
{
    __shared__ float lds[64][33];
    const int bh  = blockIdx.y;
    const int hw0 = blockIdx.x * 64;
    const int t   = threadIdx.x;

    const int hl = t >> 2, dq = (t & 3) * 8;
    const float* src = vb + ((size_t)bh * kHW + hw0 + hl) * 32 + dq;
    const float4 a = *reinterpret_cast<const float4*>(src);
    const float4 b = *reinterpret_cast<const float4*>(src + 4);
    lds[hl][dq + 0] = a.x; lds[hl][dq + 1] = a.y;
    lds[hl][dq + 2] = a.z; lds[hl][dq + 3] = a.w;
    lds[hl][dq + 4] = b.x; lds[hl][dq + 5] = b.y;
    lds[hl][dq + 6] = b.z; lds[hl][dq + 7] = b.w;
    __syncthreads();

    const int d = t >> 3, hq = (t & 7) * 8;
    ushort8v o;
    #pragma unroll
    for (int i = 0; i < 8; ++i) o[i] = f2bf_bits(lds[hq + i][d]);
    *reinterpret_cast<ushort8v*>(
        reinterpret_cast<unsigned short*>(vt) + ((size_t)bh * 32 + d) * kHW + hw0 + hq) = o;
}

// ---------------------------------------------------------------------------
// Kernel 3: LePE 5x5 depthwise conv on v (head-major in, token-major out)
// ---------------------------------------------------------------------------
__global__ __launch_bounds__(256) void lepe_kernel(
    const float* __restrict__ vb,
    const float* __restrict__ lw, const float* __restrict__ lb,
    float* __restrict__ lepe)
{
    const int c   = threadIdx.x;
    const int bhw = blockIdx.x;
    const int b   = bhw / kHW;
    const int hw  = bhw % kHW;
    const int h   = hw / kW;
    const int w   = hw % kW;
    const int head = c >> 5;
    const int d    = c & 31;

    const float* vsrc = vb + ((size_t)(b * kHeads + head) * kHW) * kHD + d;
    float acc = lb[c];
    #pragma unroll
    for (int dh = 0; dh < 5; ++dh) {
        const int h2 = h + dh - 2;
        if (h2 < 0 || h2 >= kH) continue;
        #pragma unroll
        for (int dw = 0; dw < 5; ++dw) {
            const int w2 = w + dw - 2;
            if (w2 < 0 || w2 >= kW) continue;
            acc += vsrc[(size_t)(h2 * kW + w2) * kHD] * lw[(dh * 5 + dw) * kC + c];
        }
    }
    lepe[(size_t)bhw * kC + c] = acc;
}

// ---------------------------------------------------------------------------
// Kernel 4: MFMA attention, LDS-staged (global_load_lds dbuf, counted vmcnt),
// 512 threads = 8 waves = 2 waves/SIMD. Wave w: batch b=w&3, sub-half sh=w>>2
// (2 of the 4 q-sub-tiles of the 64-row q-tile). Staging split: every wave
// stages 8 mask rows (2 gll); sh=0 waves stage K (4 gll), sh=1 stage V
// (4 gll) -> 6 gll/wave, vmcnt(6). Softmax bf16 conversion via
// v_cvt_pk_bf16_f32 (1 inst per pair instead of ~14).
// ---------------------------------------------------------------------------
__global__ __launch_bounds__(512, 1) void attn_mfma_kernel(
    const __hip_bfloat16* __restrict__ qb, const __hip_bfloat16* __restrict__ kb,
    const __hip_bfloat16* __restrict__ vt, const float* __restrict__ mask,
    float* __restrict__ po, float* __restrict__ ls, int kspan)
{
    extern __shared__ __align__(16) char smem[];   // 2 x (16K mask + 16K K + 16K V)
    constexpr int kBufStride = 49152;
    constexpr int kKOff = 16384;
    constexpr int kVOff = 32768;

    const int head = blockIdx.y;
    const int ksl  = blockIdx.z;
    const int tid  = threadIdx.x;
    const int w    = tid >> 6;          // 0..7
    const int b    = w & 3;             // batch
    const int sh   = w >> 2;            // sub-tile half: s in {2sh, 2sh+1}
    const int bh   = b * kHeads + head;
    const int lane = tid & 63;
    const int lq   = lane & 15;
    const int g    = lane >> 4;
    const int q0   = blockIdx.x * 64;
    const int kt0  = ksl * kspan;
    const int nt   = kspan >> 6;

    // Q B-fragments for this wave's 2 q-sub-tiles
    bf16x8 qfrag[2];
    #pragma unroll
    for (int si = 0; si < 2; ++si)
        qfrag[si] = *reinterpret_cast<const bf16x8*>(
            reinterpret_cast<const unsigned short*>(qb) +
            ((size_t)bh * kHW + q0 + 16 * (2 * sh + si) + lq) * kHD + g * 8);

    // staging sources (pre-swizzled; LDS written linearly -> rule #21)
    const float* msrc[2];
    #pragma unroll
    for (int i = 0; i < 2; ++i) {
        const int mrow = w * 8 + i * 4 + (lane >> 4);
        const int mcb  = (lane & 15) ^ (mrow & 7);
        msrc[i] = mask + ((size_t)head * kHW + q0 + mrow) * kHW + kt0 + mcb * 4;
    }
    const unsigned short* kvsrc[4];
    int kvstep, kvregion;
    {
        const unsigned short* kb_bh =
            reinterpret_cast<const unsigned short*>(kb) + (size_t)bh * kHW * kHD;
        const unsigned short* vt_bh =
            reinterpret_cast<const unsigned short*>(vt) + (size_t)bh * kHD * kHW;
        if (sh == 0) {   // this wave stages K for batch b
            #pragma unroll
            for (int i = 0; i < 4; ++i) {
                const int key   = i * 16 + (lane >> 2);
                const int kslot = (lane & 3) ^ (key & 3);
                kvsrc[i] = kb_bh + (size_t)(kt0 + key) * kHD + kslot * 8;
            }
            kvstep = 64 * kHD;
            kvregion = kKOff;
        } else {         // this wave stages V for batch b
            #pragma unroll
            for (int i = 0; i < 4; ++i) {
                const int d   = i * 8 + (lane >> 3);
                const int vcu = (lane & 7) ^ (d & 7);
                kvsrc[i] = vt_bh + (size_t)d * kHW + kt0 + vcu * 8;
            }
            kvstep = 64;
            kvregion = kVOff;
        }
    }

    auto STAGE = [&](int bufo, int tt) {
        char* mb = smem + bufo;
        #pragma unroll
        for (int i = 0; i < 2; ++i)
            gll16(msrc[i] + (size_t)tt * 64, mb + (w * 8 + i * 4) * 256);
        char* kv = smem + bufo + kvregion + b * 4096;
        #pragma unroll
        for (int i = 0; i < 4; ++i)
            gll16(kvsrc[i] + (size_t)tt * kvstep, kv + i * 1024);
    };

    f32x4 o0[2] = {};
    f32x4 o1[2] = {};
    float lsum[2] = {};
    const bool ghi = (g >= 2);

    // fragment read offsets (swizzled)
    const int koff = lq * 64 + ((g ^ (lq & 3)) * 16);
    const int vxa  = (g ^ (lq & 7)) * 16;
    const int vxb  = ((4 + g) ^ (lq & 7)) * 16;

    STAGE(0, 0);

    int cur = 0;
    for (int t = 0; t < nt; ++t) {
        if (t + 1 < nt) {
            STAGE(cur ^ kBufStride, t + 1);
            asm volatile("s_waitcnt vmcnt(6)" ::: "memory");
        } else {
            asm volatile("s_waitcnt vmcnt(0)" ::: "memory");
        }
        __builtin_amdgcn_s_barrier();
        __builtin_amdgcn_sched_barrier(0);

        const char* mb  = smem + cur;
        const char* kbf = smem + cur + kKOff + b * 4096;
        const char* vbf = smem + cur + kVOff + b * 4096;

        bf16x8 kf[4];
        #pragma unroll
        for (int j = 0; j < 4; ++j)
            kf[j] = *reinterpret_cast<const bf16x8*>(kbf + j * 1024 + koff);
        const bf16x8 va  = *reinterpret_cast<const bf16x8*>(vbf + lq * 128 + vxa);
        const bf16x8 vb2 = *reinterpret_cast<const bf16x8*>(vbf + lq * 128 + vxb);
        const bf16x8 vc  = *reinterpret_cast<const bf16x8*>(vbf + (16 + lq) * 128 + vxa);
        const bf16x8 vd  = *reinterpret_cast<const bf16x8*>(vbf + (16 + lq) * 128 + vxb);

        #pragma unroll
        for (int si = 0; si < 2; ++si) {
            const int s = 2 * sh + si;
            f32x4 st[4];
            #pragma unroll
            for (int j = 0; j < 4; ++j) {
                const f32x4 mc = *reinterpret_cast<const f32x4*>(
                    mb + s * 4096 + lq * 256 + (((4 * j + g) ^ (lq & 7)) * 16));
                st[j] = __builtin_amdgcn_mfma_f32_16x16x32_bf16(kf[j], qfrag[si], mc, 0, 0, 0);
            }

            unsigned p32[4][2];
            #pragma unroll
            for (int j = 0; j < 4; ++j) {
                const float e0 = __expf(st[j][0]);
                const float e1 = __expf(st[j][1]);
                const float e2 = __expf(st[j][2]);
                const float e3 = __expf(st[j][3]);
                lsum[si] += (e0 + e1) + (e2 + e3);
                p32[j][0] = cvt_pk_bf16(e0, e1);
                p32[j][1] = cvt_pk_bf16(e2, e3);
            }

            unsigned pw0[4], pw1[4];
            #pragma unroll
            for (int t2 = 0; t2 < 4; ++t2) {
                const int src = lq + 16 * (2 * (g & 1) + (t2 >> 1));
                const unsigned a0 = __shfl(p32[0][t2 & 1], src);
                const unsigned a1 = __shfl(p32[1][t2 & 1], src);
                const unsigned b0 = __shfl(p32[2][t2 & 1], src);
                const unsigned b1 = __shfl(p32[3][t2 & 1], src);
                pw0[t2] = ghi ? a1 : a0;
                pw1[t2] = ghi ? b1 : b0;
            }
            uint32x4 w0 = {pw0[0], pw0[1], pw0[2], pw0[3]};
            uint32x4 w1 = {pw1[0], pw1[1], pw1[2], pw1[3]};
            const bf16x8 pa0 = __builtin_bit_cast(bf16x8, w0);
            const bf16x8 pa1 = __builtin_bit_cast(bf16x8, w1);

            o0[si] = __builtin_amdgcn_mfma_f32_16x16x32_bf16(pa0, va,  o0[si], 0, 0, 0);
            o0[si] = __builtin_amdgcn_mfma_f32_16x16x32_bf16(pa1, vb2, o0[si], 0, 0, 0);
            o1[si] = __builtin_amdgcn_mfma_f32_16x16x32_bf16(pa0, vc,  o1[si], 0, 0, 0);
            o1[si] = __builtin_amdgcn_mfma_f32_16x16x32_bf16(pa1, vd,  o1[si], 0, 0, 0);
        }

        asm volatile("s_waitcnt lgkmcnt(0)" ::: "memory");
        __builtin_amdgcn_s_barrier();
        cur ^= kBufStride;
    }

    // per-sub-tile row-sums + un-normalized partial writes
    const size_t pbase = ((size_t)ksl * (kB * kHeads) + bh) * kHW;
    #pragma unroll
    for (int si = 0; si < 2; ++si) {
        const int s = 2 * sh + si;
        float l = lsum[si];
        l += __shfl_xor(l, 16);
        l += __shfl_xor(l, 32);
        #pragma unroll
        for (int r = 0; r < 4; ++r) {
            float* orow = po + (pbase + q0 + 16 * s + 4 * g + r) * kHD + lq;
            orow[0]  = o0[si][r];
            orow[16] = o1[si][r];
        }
        if (lane < 16) ls[pbase + q0 + 16 * s + lq] = l;
    }
}

// ---------------------------------------------------------------------------
// Kernel 4b: combine k-split partials -> normalized attn out (token-major)
// ---------------------------------------------------------------------------
__global__ __launch_bounds__(256) void combine_kernel(
    const float* __restrict__ po, const float* __restrict__ ls,
    float* __restrict__ ao, int ks)
{
    const int idx = blockIdx.x * 256 + threadIdx.x;   // over kB*kHW*kC
    const int c   = idx & 255;
    const int bhw = idx >> 8;
    const int b   = bhw / kHW;
    const int hw  = bhw % kHW;
    const int head = c >> 5;
    const int d    = c & 31;
    const int bh   = b * kHeads + head;

    float o = 0.f, l = 0.f;
    for (int s = 0; s < ks; ++s) {
        const size_t pbase = ((size_t)s * (kB * kHeads) + bh) * kHW + hw;
        o += po[pbase * kHD + d];
        l += ls[pbase];
    }
    ao[(size_t)idx] = o / l;
}

// ---------------------------------------------------------------------------
// Kernel 5: output projection GEMM, fusing (attn_out + lepe) @ Wout + bout
// ---------------------------------------------------------------------------
__global__ __launch_bounds__(256) void out_gemm_kernel(
    const float* __restrict__ a0, const float* __restrict__ a1,
    const float* __restrict__ Wo, const float* __restrict__ bo,
    float* __restrict__ out)
{
    __shared__ __align__(16) float As[16][65];
    __shared__ __align__(16) float Bs[16][65];

    const int tid = threadIdx.x;
    const int mBase = blockIdx.x * 64;
    const int nBase = blockIdx.y * 64;

    const int tx = tid & 15;
    const int ty = tid >> 4;

    const int lm  = tid >> 2;
    const int lk  = (tid & 3) * 4;
    const int lbk = tid >> 4;
    const int lbn = (tid & 15) * 4;

    float acc[4][4] = {};

    for (int k0 = 0; k0 < 256; k0 += 16) {
        const size_t aoff = (size_t)(mBase + lm) * 256 + k0 + lk;
        const float4 av0 = *reinterpret_cast<const float4*>(&a0[aoff]);
        const float4 av1 = *reinterpret_cast<const float4*>(&a1[aoff]);
        As[lk + 0][lm] = av0.x + av1.x; As[lk + 1][lm] = av0.y + av1.y;
        As[lk + 2][lm] = av0.z + av1.z; As[lk + 3][lm] = av0.w + av1.w;

        const float4 bv4 = *reinterpret_cast<const float4*>(
            &Wo[(size_t)(k0 + lbk) * 256 + nBase + lbn]);
        Bs[lbk][lbn + 0] = bv4.x; Bs[lbk][lbn + 1] = bv4.y;
        Bs[lbk][lbn + 2] = bv4.z; Bs[lbk][lbn + 3] = bv4.w;
        __syncthreads();

        #pragma unroll
        for (int kk = 0; kk < 16; ++kk) {
            float a[4], bb[4];
            #pragma unroll
            for (int i = 0; i < 4; ++i) a[i] = As[kk][ty * 4 + i];
            #pragma unroll
            for (int j = 0; j < 4; ++j) bb[j] = Bs[kk][tx * 4 + j];
            #pragma unroll
            for (int i = 0; i < 4; ++i)
                #pragma unroll
                for (int j = 0; j < 4; ++j)
                    acc[i][j] += a[i] * bb[j];
        }
        __syncthreads();
    }

    #pragma unroll
    for (int i = 0; i < 4; ++i) {
        const int m = mBase + ty * 4 + i;
        #pragma unroll
        for (int j = 0; j < 4; ++j) {
            const int n = nBase + tx * 4 + j;
            out[(size_t)m * 256 + n] = acc[i][j] + bo[n];
        }
    }
}

// ---------------------------------------------------------------------------
extern "C" void kernel_launch(void* const* d_in, const int* in_sizes, int n_in,
                              void* d_out, int out_size, void* d_ws, size_t ws_size,
                              hipStream_t stream)
{
    const float* x    = (const float*)d_in[0];
    const float* sinb = (const float*)d_in[1];
    const float* cosb = (const float*)d_in[2];
    const float* mask = (const float*)d_in[3];
    const float* Wq   = (const float*)d_in[4];
    const float* bq   = (const float*)d_in[5];
    const float* Wk   = (const float*)d_in[6];
    const float* bk   = (const float*)d_in[7];
    const float* Wv   = (const float*)d_in[8];
    const float* bv   = (const float*)d_in[9];
    const float* lw   = (const float*)d_in[10];
    const float* lb   = (const float*)d_in[11];
    const float* Wo   = (const float*)d_in[12];
    const float* bo   = (const float*)d_in[13];
    float* out = (float*)d_out;

    const size_t NT = (size_t)kB * kHeads * kHW * kHD;  // 2359296 per tensor
    const size_t fixed = NT * 4 * 3 + NT * 2 * 3;       // vb,lepe,ao + qbh,kbh,vt

    // pick k-split that fits the workspace
    int ks = 4;
    while (ks > 1) {
        const size_t need = fixed + (size_t)ks * (NT * 4 + (size_t)kB * kHeads * kHW * 4);
        if (need <= ws_size) break;
        ks >>= 1;
    }
    const int kspan = kHW / ks;

    char* base = (char*)d_ws;
    float* vb   = (float*)base;             base += NT * 4;
    float* lepe = (float*)base;             base += NT * 4;
    float* ao   = (float*)base;             base += NT * 4;
    __hip_bfloat16* qbh = (__hip_bfloat16*)base; base += NT * 2;
    __hip_bfloat16* kbh = (__hip_bfloat16*)base; base += NT * 2;
    __hip_bfloat16* vt  = (__hip_bfloat16*)base; base += NT * 2;
    float* po = (float*)base;               base += (size_t)ks * NT * 4;
    float* ls = (float*)base;               base += (size_t)ks * kB * kHeads * kHW * 4;

    qkv_gemm_kernel<<<dim3(144, 4, 3), 256, 0, stream>>>(
        x, Wq, bq, Wk, bk, Wv, bv, sinb, cosb, qbh, kbh, vb);
    vt_kernel<<<dim3(36, 32), 256, 0, stream>>>(vb, vt);
    lepe_kernel<<<dim3(9216), 256, 0, stream>>>(vb, lw, lb, lepe);
    attn_mfma_kernel<<<dim3(36, 8, ks), 512, 98304, stream>>>(
        qbh, kbh, vt, mask, po, ls, kspan);
    combine_kernel<<<dim3(9216), 256, 0, stream>>>(po, ls, ao, ks);
    out_gemm_kernel<<<dim3(144, 4), 256, 0, stream>>>(ao, lepe, Wo, bo, out);
}

// Round 9
// 208.797 us; speedup vs baseline: 1.6732x; 1.2432x over previous
//
#include <hip/hip_runtime.h>
#include <hip/hip_bf16.h>
#include <math.h>

// Problem constants
constexpr int kB     = 4;
constexpr int kH     = 48;
constexpr int kW     = 48;
constexpr int kHW    = 2304;   // 48*48
constexpr int kC     = 256;
constexpr int kHeads = 8;
constexpr int kHD    = 32;
constexpr float kScale = 0.17677669529663687f;  // 32^-0.5

typedef __bf16 bf16x8 __attribute__((ext_vector_type(8)));
typedef float  f32x4  __attribute__((ext_vector_type(4)));
typedef unsigned int   uint32x4 __attribute__((ext_vector_type(4)));
typedef unsigned short ushort8v __attribute__((ext_vector_type(8)));

static __device__ __forceinline__ unsigned short f2bf_bits(float f) {
    return __builtin_bit_cast(unsigned short, __float2bfloat16(f));
}

// packed f32x2 -> bf16x2 in one instruction (T12 primitive; no builtin on gfx950)
static __device__ __forceinline__ unsigned cvt_pk_bf16(float lo, float hi) {
    unsigned r;
    asm("v_cvt_pk_bf16_f32 %0, %1, %2" : "=v"(r) : "v"(lo), "v"(hi));
    return r;
}

// async global->LDS, 16B per lane; LDS dest = wave-uniform base + lane*16
static __device__ __forceinline__ void gll16(const void* g, void* l) {
    __builtin_amdgcn_global_load_lds(
        (const __attribute__((address_space(1))) void*)g,
        (__attribute__((address_space(3))) void*)l, 16, 0, 0);
}

// ---------------------------------------------------------------------------
// Kernel 0: prep — cast x to bf16 (token-major) + transpose Wq/Wk/Wv/Wo to
// bf16 Wt[n][k] so GEMM B-fragments are contiguous.
// ---------------------------------------------------------------------------
__global__ __launch_bounds__(256) void prep_kernel(
    const float* __restrict__ x,
    const float* __restrict__ Wq, const float* __restrict__ Wk,
    const float* __restrict__ Wv, const float* __restrict__ Wo,
    unsigned short* __restrict__ xb, unsigned short* __restrict__ wt)
{
    const int bid = blockIdx.x;
    if (bid < 2304) {                       // x: 2359296 elems, 4/thread
        const int i = (bid * 256 + threadIdx.x) * 4;
        const float4 v = *reinterpret_cast<const float4*>(x + i);
        alignas(8) unsigned short u[4] = {f2bf_bits(v.x), f2bf_bits(v.y),
                                          f2bf_bits(v.z), f2bf_bits(v.w)};
        *reinterpret_cast<unsigned long long*>(xb + i) =
            *reinterpret_cast<unsigned long long*>(u);
    } else {                                // W transpose: 4 x 65536 elems
        const int e = (bid - 2304) * 256 + threadIdx.x;
        const int m = e >> 16;
        const int r = e & 65535;
        const int k = r >> 8;
        const int n = r & 255;              // coalesced source read
        const float* W = (m == 0) ? Wq : ((m == 1) ? Wk : ((m == 2) ? Wv : Wo));
        wt[(size_t)m * 65536 + n * 256 + k] = f2bf_bits(W[k * 256 + n]);
    }
}

// ---------------------------------------------------------------------------
// Kernel 1: QKV projection via bf16 MFMA, LDS-free (fragments from global,
// x bf16 and Wt L2/L3-resident). grid (144 m-tiles of 64, 4 n-tiles of 64,
// z=3), block 256 = 4 waves; wave handles 16 tokens x 64 channels.
// Epilogue fuses bias, k-scale, RoPE (partner channel via shfl_xor 1);
// z=2 writes vt bf16 [bh][d][hw] (8B stores, replaces vt kernel) + vb fp32.
// ---------------------------------------------------------------------------
__global__ __launch_bounds__(256) void qkv_mfma_kernel(
    const unsigned short* __restrict__ xb, const unsigned short* __restrict__ wt,
    const float* __restrict__ bq, const float* __restrict__ bk,
    const float* __restrict__ bv,
    const float* __restrict__ sinb, const float* __restrict__ cosb,
    unsigned short* __restrict__ qbh, unsigned short* __restrict__ kbh,
    unsigned short* __restrict__ vt, float* __restrict__ vb)
{
    const int z = blockIdx.z;
    const unsigned short* wz = wt + (size_t)z * 65536;
    const float* bt = (z == 0) ? bq : ((z == 1) ? bk : bv);
    const int tid  = threadIdx.x;
    const int w    = tid >> 6;
    const int lane = tid & 63;
    const int l    = lane & 15;
    const int g    = lane >> 4;
    const int m0   = blockIdx.x * 64 + w * 16;   // token base of wave
    const int nb   = blockIdx.y * 64;            // channel base

    f32x4 acc[4] = {};
    const unsigned short* xrow = xb + (size_t)(m0 + l) * 256;
    #pragma unroll
    for (int kc = 0; kc < 8; ++kc) {
        const bf16x8 a = *reinterpret_cast<const bf16x8*>(xrow + kc * 32 + g * 8);
        #pragma unroll
        for (int j = 0; j < 4; ++j) {
            const bf16x8 b = *reinterpret_cast<const bf16x8*>(
                wz + (size_t)(nb + 16 * j + l) * 256 + kc * 32 + g * 8);
            acc[j] = __builtin_amdgcn_mfma_f32_16x16x32_bf16(a, b, acc[j], 0, 0, 0);
        }
    }

    // tokens handled by this lane: m0 + 4g + r
    int tok[4], bidx[4], hw[4];
    #pragma unroll
    for (int r = 0; r < 4; ++r) {
        tok[r]  = m0 + 4 * g + r;
        bidx[r] = tok[r] / kHW;
        hw[r]   = tok[r] - bidx[r] * kHW;
    }
    const float scl = (z == 1) ? kScale : 1.0f;

    if (z == 2) {
        #pragma unroll
        for (int j = 0; j < 4; ++j) {
            const int c = nb + 16 * j + l;
            const int head = c >> 5, d = c & 31;
            const float bias = bt[c];
            float t[4];
            #pragma unroll
            for (int r = 0; r < 4; ++r) t[r] = acc[j][r] + bias;
            // vb fp32 head-major (lepe input)
            #pragma unroll
            for (int r = 0; r < 4; ++r)
                vb[(((size_t)(bidx[r] * kHeads + head) * kHW + hw[r]) << 5) + d] = t[r];
            // vt bf16 [bh][d][hw]: 4 consecutive tokens (same batch: 16 | 2304)
            alignas(8) unsigned short u[4] = {f2bf_bits(t[0]), f2bf_bits(t[1]),
                                              f2bf_bits(t[2]), f2bf_bits(t[3])};
            *reinterpret_cast<unsigned long long*>(
                vt + ((size_t)(bidx[0] * kHeads + head) * kHD + d) * kHW + hw[0]) =
                *reinterpret_cast<unsigned long long*>(u);
        }
    } else {
        unsigned short* ob = (z == 0) ? qbh : kbh;
        #pragma unroll
        for (int j = 0; j < 4; ++j) {
            const int c = nb + 16 * j + l;
            const int head = c >> 5, d = c & 31;
            const float bias = bt[c];
            float t[4];
            #pragma unroll
            for (int r = 0; r < 4; ++r) t[r] = (acc[j][r] + bias) * scl;
            // RoPE: partner channel c^1 lives in lane^1 (same g, r)
            #pragma unroll
            for (int r = 0; r < 4; ++r) {
                const float p = __shfl_xor(t[r], 1);
                const float cs = cosb[hw[r] * 32 + d];
                const float sn = sinb[hw[r] * 32 + d];
                const float o = (d & 1) ? (t[r] * cs + p * sn)
                                        : (t[r] * cs - p * sn);
                ob[(((size_t)(bidx[r] * kHeads + head) * kHW + hw[r]) << 5) + d] =
                    f2bf_bits(o);
            }
        }
    }
}

// ---------------------------------------------------------------------------
// Kernel 3: LePE 5x5 depthwise conv on v (head-major in, token-major out)
// ---------------------------------------------------------------------------
__global__ __launch_bounds__(256) void lepe_kernel(
    const float* __restrict__ vb,
    const float* __restrict__ lw, const float* __restrict__ lb,
    float* __restrict__ lepe)
{
    const int c   = threadIdx.x;
    const int bhw = blockIdx.x;
    const int b   = bhw / kHW;
    const int hw  = bhw % kHW;
    const int h   = hw / kW;
    const int w   = hw % kW;
    const int head = c >> 5;
    const int d    = c & 31;

    const float* vsrc = vb + ((size_t)(b * kHeads + head) * kHW) * kHD + d;
    float acc = lb[c];
    #pragma unroll
    for (int dh = 0; dh < 5; ++dh) {
        const int h2 = h + dh - 2;
        if (h2 < 0 || h2 >= kH) continue;
        #pragma unroll
        for (int dw = 0; dw < 5; ++dw) {
            const int w2 = w + dw - 2;
            if (w2 < 0 || w2 >= kW) continue;
            acc += vsrc[(size_t)(h2 * kW + w2) * kHD] * lw[(dh * 5 + dw) * kC + c];
        }
    }
    lepe[(size_t)bhw * kC + c] = acc;
}

// ---------------------------------------------------------------------------
// Kernel 4: MFMA attention (unchanged from R8): LDS-staged dbuf, counted
// vmcnt, 512 threads = 8 waves (batch x sub-half), cvt_pk softmax.
// ---------------------------------------------------------------------------
__global__ __launch_bounds__(512, 1) void attn_mfma_kernel(
    const __hip_bfloat16* __restrict__ qb, const __hip_bfloat16* __restrict__ kb,
    const __hip_bfloat16* __restrict__ vt, const float* __restrict__ mask,
    float* __restrict__ po, float* __restrict__ ls, int kspan)
{
    extern __shared__ __align__(16) char smem[];   // 2 x (16K mask + 16K K + 16K V)
    constexpr int kBufStride = 49152;
    constexpr int kKOff = 16384;
    constexpr int kVOff = 32768;

    const int head = blockIdx.y;
    const int ksl  = blockIdx.z;
    const int tid  = threadIdx.x;
    const int w    = tid >> 6;          // 0..7
    const int b    = w & 3;             // batch
    const int sh   = w >> 2;            // sub-tile half: s in {2sh, 2sh+1}
    const int bh   = b * kHeads + head;
    const int lane = tid & 63;
    const int lq   = lane & 15;
    const int g    = lane >> 4;
    const int q0   = blockIdx.x * 64;
    const int kt0  = ksl * kspan;
    const int nt   = kspan >> 6;

    bf16x8 qfrag[2];
    #pragma unroll
    for (int si = 0; si < 2; ++si)
        qfrag[si] = *reinterpret_cast<const bf16x8*>(
            reinterpret_cast<const unsigned short*>(qb) +
            ((size_t)bh * kHW + q0 + 16 * (2 * sh + si) + lq) * kHD + g * 8);

    const float* msrc[2];
    #pragma unroll
    for (int i = 0; i < 2; ++i) {
        const int mrow = w * 8 + i * 4 + (lane >> 4);
        const int mcb  = (lane & 15) ^ (mrow & 7);
        msrc[i] = mask + ((size_t)head * kHW + q0 + mrow) * kHW + kt0 + mcb * 4;
    }
    const unsigned short* kvsrc[4];
    int kvstep, kvregion;
    {
        const unsigned short* kb_bh =
            reinterpret_cast<const unsigned short*>(kb) + (size_t)bh * kHW * kHD;
        const unsigned short* vt_bh =
            reinterpret_cast<const unsigned short*>(vt) + (size_t)bh * kHD * kHW;
        if (sh == 0) {
            #pragma unroll
            for (int i = 0; i < 4; ++i) {
                const int key   = i * 16 + (lane >> 2);
                const int kslot = (lane & 3) ^ (key & 3);
                kvsrc[i] = kb_bh + (size_t)(kt0 + key) * kHD + kslot * 8;
            }
            kvstep = 64 * kHD;
            kvregion = kKOff;
        } else {
            #pragma unroll
            for (int i = 0; i < 4; ++i) {
                const int d   = i * 8 + (lane >> 3);
                const int vcu = (lane & 7) ^ (d & 7);
                kvsrc[i] = vt_bh + (size_t)d * kHW + kt0 + vcu * 8;
            }
            kvstep = 64;
            kvregion = kVOff;
        }
    }

    auto STAGE = [&](int bufo, int tt) {
        char* mb = smem + bufo;
        #pragma unroll
        for (int i = 0; i < 2; ++i)
            gll16(msrc[i] + (size_t)tt * 64, mb + (w * 8 + i * 4) * 256);
        char* kv = smem + bufo + kvregion + b * 4096;
        #pragma unroll
        for (int i = 0; i < 4; ++i)
            gll16(kvsrc[i] + (size_t)tt * kvstep, kv + i * 1024);
    };

    f32x4 o0[2] = {};
    f32x4 o1[2] = {};
    float lsum[2] = {};
    const bool ghi = (g >= 2);

    const int koff = lq * 64 + ((g ^ (lq & 3)) * 16);
    const int vxa  = (g ^ (lq & 7)) * 16;
    const int vxb  = ((4 + g) ^ (lq & 7)) * 16;

    STAGE(0, 0);

    int cur = 0;
    for (int t = 0; t < nt; ++t) {
        if (t + 1 < nt) {
            STAGE(cur ^ kBufStride, t + 1);
            asm volatile("s_waitcnt vmcnt(6)" ::: "memory");
        } else {
            asm volatile("s_waitcnt vmcnt(0)" ::: "memory");
        }
        __builtin_amdgcn_s_barrier();
        __builtin_amdgcn_sched_barrier(0);

        const char* mb  = smem + cur;
        const char* kbf = smem + cur + kKOff + b * 4096;
        const char* vbf = smem + cur + kVOff + b * 4096;

        bf16x8 kf[4];
        #pragma unroll
        for (int j = 0; j < 4; ++j)
            kf[j] = *reinterpret_cast<const bf16x8*>(kbf + j * 1024 + koff);
        const bf16x8 va  = *reinterpret_cast<const bf16x8*>(vbf + lq * 128 + vxa);
        const bf16x8 vb2 = *reinterpret_cast<const bf16x8*>(vbf + lq * 128 + vxb);
        const bf16x8 vc  = *reinterpret_cast<const bf16x8*>(vbf + (16 + lq) * 128 + vxa);
        const bf16x8 vd  = *reinterpret_cast<const bf16x8*>(vbf + (16 + lq) * 128 + vxb);

        #pragma unroll
        for (int si = 0; si < 2; ++si) {
            const int s = 2 * sh + si;
            f32x4 st[4];
            #pragma unroll
            for (int j = 0; j < 4; ++j) {
                const f32x4 mc = *reinterpret_cast<const f32x4*>(
                    mb + s * 4096 + lq * 256 + (((4 * j + g) ^ (lq & 7)) * 16));
                st[j] = __builtin_amdgcn_mfma_f32_16x16x32_bf16(kf[j], qfrag[si], mc, 0, 0, 0);
            }

            unsigned p32[4][2];
            #pragma unroll
            for (int j = 0; j < 4; ++j) {
                const float e0 = __expf(st[j][0]);
                const float e1 = __expf(st[j][1]);
                const float e2 = __expf(st[j][2]);
                const float e3 = __expf(st[j][3]);
                lsum[si] += (e0 + e1) + (e2 + e3);
                p32[j][0] = cvt_pk_bf16(e0, e1);
                p32[j][1] = cvt_pk_bf16(e2, e3);
            }

            unsigned pw0[4], pw1[4];
            #pragma unroll
            for (int t2 = 0; t2 < 4; ++t2) {
                const int src = lq + 16 * (2 * (g & 1) + (t2 >> 1));
                const unsigned a0 = __shfl(p32[0][t2 & 1], src);
                const unsigned a1 = __shfl(p32[1][t2 & 1], src);
                const unsigned b0 = __shfl(p32[2][t2 & 1], src);
                const unsigned b1 = __shfl(p32[3][t2 & 1], src);
                pw0[t2] = ghi ? a1 : a0;
                pw1[t2] = ghi ? b1 : b0;
            }
            uint32x4 w0 = {pw0[0], pw0[1], pw0[2], pw0[3]};
            uint32x4 w1 = {pw1[0], pw1[1], pw1[2], pw1[3]};
            const bf16x8 pa0 = __builtin_bit_cast(bf16x8, w0);
            const bf16x8 pa1 = __builtin_bit_cast(bf16x8, w1);

            o0[si] = __builtin_amdgcn_mfma_f32_16x16x32_bf16(pa0, va,  o0[si], 0, 0, 0);
            o0[si] = __builtin_amdgcn_mfma_f32_16x16x32_bf16(pa1, vb2, o0[si], 0, 0, 0);
            o1[si] = __builtin_amdgcn_mfma_f32_16x16x32_bf16(pa0, vc,  o1[si], 0, 0, 0);
            o1[si] = __builtin_amdgcn_mfma_f32_16x16x32_bf16(pa1, vd,  o1[si], 0, 0, 0);
        }

        asm volatile("s_waitcnt lgkmcnt(0)" ::: "memory");
        __builtin_amdgcn_s_barrier();
        cur ^= kBufStride;
    }

    const size_t pbase = ((size_t)ksl * (kB * kHeads) + bh) * kHW;
    #pragma unroll
    for (int si = 0; si < 2; ++si) {
        const int s = 2 * sh + si;
        float l = lsum[si];
        l += __shfl_xor(l, 16);
        l += __shfl_xor(l, 32);
        #pragma unroll
        for (int r = 0; r < 4; ++r) {
            float* orow = po + (pbase + q0 + 16 * s + 4 * g + r) * kHD + lq;
            orow[0]  = o0[si][r];
            orow[16] = o1[si][r];
        }
        if (lane < 16) ls[pbase + q0 + 16 * s + lq] = l;
    }
}

// ---------------------------------------------------------------------------
// Kernel 4b: combine k-split partials + lepe add -> bf16 A matrix for out proj
// ---------------------------------------------------------------------------
__global__ __launch_bounds__(256) void combine_kernel(
    const float* __restrict__ po, const float* __restrict__ ls,
    const float* __restrict__ lepe, unsigned short* __restrict__ abh, int ks)
{
    const int idx = blockIdx.x * 256 + threadIdx.x;   // over kB*kHW*kC
    const int c   = idx & 255;
    const int bhw = idx >> 8;
    const int b   = bhw / kHW;
    const int hw  = bhw % kHW;
    const int head = c >> 5;
    const int d    = c & 31;
    const int bh   = b * kHeads + head;

    float o = 0.f, l = 0.f;
    for (int s = 0; s < ks; ++s) {
        const size_t pbase = ((size_t)s * (kB * kHeads) + bh) * kHW + hw;
        o += po[pbase * kHD + d];
        l += ls[pbase];
    }
    abh[(size_t)idx] = f2bf_bits(o / l + lepe[idx]);
}

// ---------------------------------------------------------------------------
// Kernel 5: output projection via bf16 MFMA (same skeleton as qkv_mfma).
// ---------------------------------------------------------------------------
__global__ __launch_bounds__(256) void out_mfma_kernel(
    const unsigned short* __restrict__ abh, const unsigned short* __restrict__ wt,
    const float* __restrict__ bo, float* __restrict__ out)
{
    const unsigned short* wz = wt + (size_t)3 * 65536;
    const int tid  = threadIdx.x;
    const int w    = tid >> 6;
    const int lane = tid & 63;
    const int l    = lane & 15;
    const int g    = lane >> 4;
    const int m0   = blockIdx.x * 64 + w * 16;
    const int nb   = blockIdx.y * 64;

    f32x4 acc[4] = {};
    const unsigned short* arow = abh + (size_t)(m0 + l) * 256;
    #pragma unroll
    for (int kc = 0; kc < 8; ++kc) {
        const bf16x8 a = *reinterpret_cast<const bf16x8*>(arow + kc * 32 + g * 8);
        #pragma unroll
        for (int j = 0; j < 4; ++j) {
            const bf16x8 b = *reinterpret_cast<const bf16x8*>(
                wz + (size_t)(nb + 16 * j + l) * 256 + kc * 32 + g * 8);
            acc[j] = __builtin_amdgcn_mfma_f32_16x16x32_bf16(a, b, acc[j], 0, 0, 0);
        }
    }

    #pragma unroll
    for (int j = 0; j < 4; ++j) {
        const int c = nb + 16 * j + l;
        const float bias = bo[c];
        #pragma unroll
        for (int r = 0; r < 4; ++r)
            out[(size_t)(m0 + 4 * g + r) * 256 + c] = acc[j][r] + bias;
    }
}

// ---------------------------------------------------------------------------
extern "C" void kernel_launch(void* const* d_in, const int* in_sizes, int n_in,
                              void* d_out, int out_size, void* d_ws, size_t ws_size,
                              hipStream_t stream)
{
    const float* x    = (const float*)d_in[0];
    const float* sinb = (const float*)d_in[1];
    const float* cosb = (const float*)d_in[2];
    const float* mask = (const float*)d_in[3];
    const float* Wq   = (const float*)d_in[4];
    const float* bq   = (const float*)d_in[5];
    const float* Wk   = (const float*)d_in[6];
    const float* bk   = (const float*)d_in[7];
    const float* Wv   = (const float*)d_in[8];
    const float* bv   = (const float*)d_in[9];
    const float* lw   = (const float*)d_in[10];
    const float* lb   = (const float*)d_in[11];
    const float* Wo   = (const float*)d_in[12];
    const float* bo   = (const float*)d_in[13];
    float* out = (float*)d_out;

    const size_t NT = (size_t)kB * kHeads * kHW * kHD;  // 2359296 per tensor
    // fixed: vb, lepe (f32) + xb, abh, qbh, kbh, vt (bf16) + wt (512KB)
    const size_t fixed = NT * 4 * 2 + NT * 2 * 5 + 4 * 65536 * 2;

    int ks = 4;
    while (ks > 1) {
        const size_t need = fixed + (size_t)ks * (NT * 4 + (size_t)kB * kHeads * kHW * 4);
        if (need <= ws_size) break;
        ks >>= 1;
    }
    const int kspan = kHW / ks;

    char* base = (char*)d_ws;
    float* vb   = (float*)base;                      base += NT * 4;
    float* lepe = (float*)base;                      base += NT * 4;
    unsigned short* xb  = (unsigned short*)base;     base += NT * 2;
    unsigned short* abh = (unsigned short*)base;     base += NT * 2;
    unsigned short* qbh = (unsigned short*)base;     base += NT * 2;
    unsigned short* kbh = (unsigned short*)base;     base += NT * 2;
    unsigned short* vt  = (unsigned short*)base;     base += NT * 2;
    unsigned short* wt  = (unsigned short*)base;     base += (size_t)4 * 65536 * 2;
    float* po = (float*)base;                        base += (size_t)ks * NT * 4;
    float* ls = (float*)base;                        base += (size_t)ks * kB * kHeads * kHW * 4;

    prep_kernel<<<dim3(3328), 256, 0, stream>>>(x, Wq, Wk, Wv, Wo, xb, wt);
    qkv_mfma_kernel<<<dim3(144, 4, 3), 256, 0, stream>>>(
        xb, wt, bq, bk, bv, sinb, cosb, qbh, kbh, vt, vb);
    lepe_kernel<<<dim3(9216), 256, 0, stream>>>(vb, lw, lb, lepe);
    attn_mfma_kernel<<<dim3(36, 8, ks), 512, 98304, stream>>>(
        (const __hip_bfloat16*)qbh, (const __hip_bfloat16*)kbh,
        (const __hip_bfloat16*)vt, mask, po, ls, kspan);
    combine_kernel<<<dim3(9216), 256, 0, stream>>>(po, ls, lepe, abh, ks);
    out_mfma_kernel<<<dim3(144, 4), 256, 0, stream>>>(abh, wt, bo, out);
}

// Round 10
// 186.622 us; speedup vs baseline: 1.8720x; 1.1188x over previous
//
#include <hip/hip_runtime.h>
#include <hip/hip_bf16.h>
#include <math.h>

// Problem constants
constexpr int kB     = 4;
constexpr int kH     = 48;
constexpr int kW     = 48;
constexpr int kHW    = 2304;   // 48*48
constexpr int kC     = 256;
constexpr int kHeads = 8;
constexpr int kHD    = 32;
constexpr float kScale = 0.17677669529663687f;  // 32^-0.5

typedef __bf16 bf16x8 __attribute__((ext_vector_type(8)));
typedef float  f32x4  __attribute__((ext_vector_type(4)));
typedef unsigned int   uint32x4 __attribute__((ext_vector_type(4)));
typedef unsigned short ushort8v __attribute__((ext_vector_type(8)));

static __device__ __forceinline__ unsigned short f2bf_bits(float f) {
    return __builtin_bit_cast(unsigned short, __float2bfloat16(f));
}

// packed f32x2 -> bf16x2 in one instruction
static __device__ __forceinline__ unsigned cvt_pk_bf16(float lo, float hi) {
    unsigned r;
    asm("v_cvt_pk_bf16_f32 %0, %1, %2" : "=v"(r) : "v"(lo), "v"(hi));
    return r;
}

// VALU cross-lane swaps (gfx950): a.g1<->b.g0, a.g3<->b.g2 (16) ; a.g23<->b.g01 (32)
static __device__ __forceinline__ void permlane16_swap(unsigned& a, unsigned& b) {
    asm("v_permlane16_swap_b32 %0, %1" : "+v"(a), "+v"(b));
}
static __device__ __forceinline__ void permlane32_swap(unsigned& a, unsigned& b) {
    asm("v_permlane32_swap_b32 %0, %1" : "+v"(a), "+v"(b));
}

// async global->LDS, 16B per lane; LDS dest = wave-uniform base + lane*16
static __device__ __forceinline__ void gll16(const void* g, void* l) {
    __builtin_amdgcn_global_load_lds(
        (const __attribute__((address_space(1))) void*)g,
        (__attribute__((address_space(3))) void*)l, 16, 0, 0);
}

// ---------------------------------------------------------------------------
// Kernel 0: prep — cast x to bf16 + transpose Wq/Wk/Wv/Wo to bf16 Wt[n][k].
// ---------------------------------------------------------------------------
__global__ __launch_bounds__(256) void prep_kernel(
    const float* __restrict__ x,
    const float* __restrict__ Wq, const float* __restrict__ Wk,
    const float* __restrict__ Wv, const float* __restrict__ Wo,
    unsigned short* __restrict__ xb, unsigned short* __restrict__ wt)
{
    const int bid = blockIdx.x;
    if (bid < 2304) {
        const int i = (bid * 256 + threadIdx.x) * 4;
        const float4 v = *reinterpret_cast<const float4*>(x + i);
        alignas(8) unsigned short u[4] = {f2bf_bits(v.x), f2bf_bits(v.y),
                                          f2bf_bits(v.z), f2bf_bits(v.w)};
        *reinterpret_cast<unsigned long long*>(xb + i) =
            *reinterpret_cast<unsigned long long*>(u);
    } else {
        const int e = (bid - 2304) * 256 + threadIdx.x;
        const int m = e >> 16;
        const int r = e & 65535;
        const int k = r >> 8;
        const int n = r & 255;
        const float* W = (m == 0) ? Wq : ((m == 1) ? Wk : ((m == 2) ? Wv : Wo));
        wt[(size_t)m * 65536 + n * 256 + k] = f2bf_bits(W[k * 256 + n]);
    }
}

// ---------------------------------------------------------------------------
// Kernel 1: QKV projection via bf16 MFMA (fused bias/scale/RoPE; z=2 emits
// vt bf16 [bh][d][hw] + vb fp32).
// ---------------------------------------------------------------------------
__global__ __launch_bounds__(256) void qkv_mfma_kernel(
    const unsigned short* __restrict__ xb, const unsigned short* __restrict__ wt,
    const float* __restrict__ bq, const float* __restrict__ bk,
    const float* __restrict__ bv,
    const float* __restrict__ sinb, const float* __restrict__ cosb,
    unsigned short* __restrict__ qbh, unsigned short* __restrict__ kbh,
    unsigned short* __restrict__ vt, float* __restrict__ vb)
{
    const int z = blockIdx.z;
    const unsigned short* wz = wt + (size_t)z * 65536;
    const float* bt = (z == 0) ? bq : ((z == 1) ? bk : bv);
    const int tid  = threadIdx.x;
    const int w    = tid >> 6;
    const int lane = tid & 63;
    const int l    = lane & 15;
    const int g    = lane >> 4;
    const int m0   = blockIdx.x * 64 + w * 16;
    const int nb   = blockIdx.y * 64;

    f32x4 acc[4] = {};
    const unsigned short* xrow = xb + (size_t)(m0 + l) * 256;
    #pragma unroll
    for (int kc = 0; kc < 8; ++kc) {
        const bf16x8 a = *reinterpret_cast<const bf16x8*>(xrow + kc * 32 + g * 8);
        #pragma unroll
        for (int j = 0; j < 4; ++j) {
            const bf16x8 b = *reinterpret_cast<const bf16x8*>(
                wz + (size_t)(nb + 16 * j + l) * 256 + kc * 32 + g * 8);
            acc[j] = __builtin_amdgcn_mfma_f32_16x16x32_bf16(a, b, acc[j], 0, 0, 0);
        }
    }

    int tok[4], bidx[4], hw[4];
    #pragma unroll
    for (int r = 0; r < 4; ++r) {
        tok[r]  = m0 + 4 * g + r;
        bidx[r] = tok[r] / kHW;
        hw[r]   = tok[r] - bidx[r] * kHW;
    }
    const float scl = (z == 1) ? kScale : 1.0f;

    if (z == 2) {
        #pragma unroll
        for (int j = 0; j < 4; ++j) {
            const int c = nb + 16 * j + l;
            const int head = c >> 5, d = c & 31;
            const float bias = bt[c];
            float t[4];
            #pragma unroll
            for (int r = 0; r < 4; ++r) t[r] = acc[j][r] + bias;
            #pragma unroll
            for (int r = 0; r < 4; ++r)
                vb[(((size_t)(bidx[r] * kHeads + head) * kHW + hw[r]) << 5) + d] = t[r];
            alignas(8) unsigned short u[4] = {f2bf_bits(t[0]), f2bf_bits(t[1]),
                                              f2bf_bits(t[2]), f2bf_bits(t[3])};
            *reinterpret_cast<unsigned long long*>(
                vt + ((size_t)(bidx[0] * kHeads + head) * kHD + d) * kHW + hw[0]) =
                *reinterpret_cast<unsigned long long*>(u);
        }
    } else {
        unsigned short* ob = (z == 0) ? qbh : kbh;
        #pragma unroll
        for (int j = 0; j < 4; ++j) {
            const int c = nb + 16 * j + l;
            const int head = c >> 5, d = c & 31;
            const float bias = bt[c];
            float t[4];
            #pragma unroll
            for (int r = 0; r < 4; ++r) t[r] = (acc[j][r] + bias) * scl;
            #pragma unroll
            for (int r = 0; r < 4; ++r) {
                const float p = __shfl_xor(t[r], 1);
                const float cs = cosb[hw[r] * 32 + d];
                const float sn = sinb[hw[r] * 32 + d];
                const float o = (d & 1) ? (t[r] * cs + p * sn)
                                        : (t[r] * cs - p * sn);
                ob[(((size_t)(bidx[r] * kHeads + head) * kHW + hw[r]) << 5) + d] =
                    f2bf_bits(o);
            }
        }
    }
}

// ---------------------------------------------------------------------------
// Kernel 3: LePE 5x5 depthwise conv on v (head-major in, token-major out)
// ---------------------------------------------------------------------------
__global__ __launch_bounds__(256) void lepe_kernel(
    const float* __restrict__ vb,
    const float* __restrict__ lw, const float* __restrict__ lb,
    float* __restrict__ lepe)
{
    const int c   = threadIdx.x;
    const int bhw = blockIdx.x;
    const int b   = bhw / kHW;
    const int hw  = bhw % kHW;
    const int h   = hw / kW;
    const int w   = hw % kW;
    const int head = c >> 5;
    const int d    = c & 31;

    const float* vsrc = vb + ((size_t)(b * kHeads + head) * kHW) * kHD + d;
    float acc = lb[c];
    #pragma unroll
    for (int dh = 0; dh < 5; ++dh) {
        const int h2 = h + dh - 2;
        if (h2 < 0 || h2 >= kH) continue;
        #pragma unroll
        for (int dw = 0; dw < 5; ++dw) {
            const int w2 = w + dw - 2;
            if (w2 < 0 || w2 >= kW) continue;
            acc += vsrc[(size_t)(h2 * kW + w2) * kHD] * lw[(dh * 5 + dw) * kC + c];
        }
    }
    lepe[(size_t)bhw * kC + c] = acc;
}

// ---------------------------------------------------------------------------
// Kernel 4: MFMA attention, 32-row q-tile -> 80KB LDS -> 2 blocks/CU.
// 512 threads = 8 waves: wave w = (batch b=w&3, sub-tile sh=w>>2 of 2).
// Staging/wave: 1 mask gll + 4 K or V glls = 5 (vmcnt(5) counted dbuf).
// P redistribution via VALU permlane16/32_swap + group cndmask (no LDS pipe).
// ---------------------------------------------------------------------------
__global__ __launch_bounds__(512, 4) void attn_mfma_kernel(
    const __hip_bfloat16* __restrict__ qb, const __hip_bfloat16* __restrict__ kb,
    const __hip_bfloat16* __restrict__ vt, const float* __restrict__ mask,
    float* __restrict__ po, float* __restrict__ ls, int kspan)
{
    extern __shared__ __align__(16) char smem[];   // 2 x (8K mask + 16K K + 16K V)
    constexpr int kBufStride = 40960;
    constexpr int kKOff = 8192;
    constexpr int kVOff = 24576;

    const int head = blockIdx.y;
    const int ksl  = blockIdx.z;
    const int tid  = threadIdx.x;
    const int w    = tid >> 6;          // 0..7
    const int b    = w & 3;             // batch
    const int sh   = w >> 2;            // this wave's q-sub-tile (0 or 1)
    const int bh   = b * kHeads + head;
    const int lane = tid & 63;
    const int lq   = lane & 15;
    const int g    = lane >> 4;
    const int q0   = blockIdx.x * 32;
    const int kt0  = ksl * kspan;
    const int nt   = kspan >> 6;
    const bool odd16 = (g & 1);

    // Q B-fragment for this wave's sub-tile
    const bf16x8 qfrag = *reinterpret_cast<const bf16x8*>(
        reinterpret_cast<const unsigned short*>(qb) +
        ((size_t)bh * kHW + q0 + 16 * sh + lq) * kHD + g * 8);

    // staging sources (pre-swizzled; LDS written linearly)
    const float* msrc;
    {
        const int mrow = w * 4 + (lane >> 4);
        const int mcb  = (lane & 15) ^ (mrow & 7);
        msrc = mask + ((size_t)head * kHW + q0 + mrow) * kHW + kt0 + mcb * 4;
    }
    const unsigned short* kvsrc[4];
    int kvstep, kvregion;
    {
        const unsigned short* kb_bh =
            reinterpret_cast<const unsigned short*>(kb) + (size_t)bh * kHW * kHD;
        const unsigned short* vt_bh =
            reinterpret_cast<const unsigned short*>(vt) + (size_t)bh * kHD * kHW;
        if (sh == 0) {   // waves 0..3 stage K for their batch
            #pragma unroll
            for (int i = 0; i < 4; ++i) {
                const int key   = i * 16 + (lane >> 2);
                const int kslot = (lane & 3) ^ (key & 3);
                kvsrc[i] = kb_bh + (size_t)(kt0 + key) * kHD + kslot * 8;
            }
            kvstep = 64 * kHD;
            kvregion = kKOff;
        } else {         // waves 4..7 stage V
            #pragma unroll
            for (int i = 0; i < 4; ++i) {
                const int d   = i * 8 + (lane >> 3);
                const int vcu = (lane & 7) ^ (d & 7);
                kvsrc[i] = vt_bh + (size_t)d * kHW + kt0 + vcu * 8;
            }
            kvstep = 64;
            kvregion = kVOff;
        }
    }

    auto STAGE = [&](int bufo, int tt) {
        gll16(msrc + (size_t)tt * 64, smem + bufo + w * 1024);
        char* kv = smem + bufo + kvregion + b * 4096;
        #pragma unroll
        for (int i = 0; i < 4; ++i)
            gll16(kvsrc[i] + (size_t)tt * kvstep, kv + i * 1024);
    };

    f32x4 o0 = {0.f, 0.f, 0.f, 0.f};
    f32x4 o1 = {0.f, 0.f, 0.f, 0.f};
    float lsum = 0.f;

    // swizzled fragment read offsets
    const int koff = lq * 64 + ((g ^ (lq & 3)) * 16);
    const int vxa  = (g ^ (lq & 7)) * 16;
    const int vxb  = ((4 + g) ^ (lq & 7)) * 16;

    STAGE(0, 0);

    int cur = 0;
    for (int t = 0; t < nt; ++t) {
        if (t + 1 < nt) {
            STAGE(cur ^ kBufStride, t + 1);
            asm volatile("s_waitcnt vmcnt(5)" ::: "memory");
        } else {
            asm volatile("s_waitcnt vmcnt(0)" ::: "memory");
        }
        __builtin_amdgcn_s_barrier();
        __builtin_amdgcn_sched_barrier(0);

        const char* mb  = smem + cur;
        const char* kbf = smem + cur + kKOff + b * 4096;
        const char* vbf = smem + cur + kVOff + b * 4096;

        bf16x8 kf[4];
        #pragma unroll
        for (int j = 0; j < 4; ++j)
            kf[j] = *reinterpret_cast<const bf16x8*>(kbf + j * 1024 + koff);
        const bf16x8 va  = *reinterpret_cast<const bf16x8*>(vbf + lq * 128 + vxa);
        const bf16x8 vb2 = *reinterpret_cast<const bf16x8*>(vbf + lq * 128 + vxb);
        const bf16x8 vc  = *reinterpret_cast<const bf16x8*>(vbf + (16 + lq) * 128 + vxa);
        const bf16x8 vd  = *reinterpret_cast<const bf16x8*>(vbf + (16 + lq) * 128 + vxb);

        f32x4 st[4];
        #pragma unroll
        for (int j = 0; j < 4; ++j) {
            const f32x4 mc = *reinterpret_cast<const f32x4*>(
                mb + sh * 4096 + lq * 256 + (((4 * j + g) ^ (lq & 7)) * 16));
            st[j] = __builtin_amdgcn_mfma_f32_16x16x32_bf16(kf[j], qfrag, mc, 0, 0, 0);
        }

        unsigned p32[4][2];
        #pragma unroll
        for (int j = 0; j < 4; ++j) {
            const float e0 = __expf(st[j][0]);
            const float e1 = __expf(st[j][1]);
            const float e2 = __expf(st[j][2]);
            const float e3 = __expf(st[j][3]);
            lsum += (e0 + e1) + (e2 + e3);
            p32[j][0] = cvt_pk_bf16(e0, e1);
            p32[j][1] = cvt_pk_bf16(e2, e3);
        }

        // P redistribution (S^T lane layout -> PV A-fragment layout), pure VALU:
        // s[j][r][0] = [P0,P0,P2,P2], s[j][r][1] = [P1,P1,P3,P3] (16-groups)
        unsigned sj[4][2][2];
        #pragma unroll
        for (int j = 0; j < 4; ++j)
            #pragma unroll
            for (int r = 0; r < 2; ++r) {
                unsigned a = p32[j][r], b2 = p32[j][r];
                permlane16_swap(a, b2);
                sj[j][r][0] = a; sj[j][r][1] = b2;
            }
        unsigned pw0[4], pw1[4];
        #pragma unroll
        for (int w2 = 0; w2 < 4; ++w2) {
            const int r = w2 & 1, c = w2 >> 1;
            unsigned pa = sj[0][r][c], pb = sj[1][r][c];
            permlane32_swap(pa, pb);
            pw0[w2] = odd16 ? pb : pa;
            unsigned qa = sj[2][r][c], qb2 = sj[3][r][c];
            permlane32_swap(qa, qb2);
            pw1[w2] = odd16 ? qb2 : qa;
        }
        uint32x4 w0v = {pw0[0], pw0[1], pw0[2], pw0[3]};
        uint32x4 w1v = {pw1[0], pw1[1], pw1[2], pw1[3]};
        const bf16x8 pa0 = __builtin_bit_cast(bf16x8, w0v);
        const bf16x8 pa1 = __builtin_bit_cast(bf16x8, w1v);

        o0 = __builtin_amdgcn_mfma_f32_16x16x32_bf16(pa0, va,  o0, 0, 0, 0);
        o0 = __builtin_amdgcn_mfma_f32_16x16x32_bf16(pa1, vb2, o0, 0, 0, 0);
        o1 = __builtin_amdgcn_mfma_f32_16x16x32_bf16(pa0, vc,  o1, 0, 0, 0);
        o1 = __builtin_amdgcn_mfma_f32_16x16x32_bf16(pa1, vd,  o1, 0, 0, 0);

        asm volatile("s_waitcnt lgkmcnt(0)" ::: "memory");
        __builtin_amdgcn_s_barrier();
        cur ^= kBufStride;
    }

    // row-sum (partial over this k-range) + un-normalized partial writes
    lsum += __shfl_xor(lsum, 16);
    lsum += __shfl_xor(lsum, 32);

    const size_t pbase = ((size_t)ksl * (kB * kHeads) + bh) * kHW;
    #pragma unroll
    for (int r = 0; r < 4; ++r) {
        float* orow = po + (pbase + q0 + 16 * sh + 4 * g + r) * kHD + lq;
        orow[0]  = o0[r];
        orow[16] = o1[r];
    }
    if (lane < 16) ls[pbase + q0 + 16 * sh + lq] = lsum;
}

// ---------------------------------------------------------------------------
// Kernel 4b: combine k-split partials + lepe add -> bf16 A matrix for out proj
// ---------------------------------------------------------------------------
__global__ __launch_bounds__(256) void combine_kernel(
    const float* __restrict__ po, const float* __restrict__ ls,
    const float* __restrict__ lepe, unsigned short* __restrict__ abh, int ks)
{
    const int idx = blockIdx.x * 256 + threadIdx.x;
    const int c   = idx & 255;
    const int bhw = idx >> 8;
    const int b   = bhw / kHW;
    const int hw  = bhw % kHW;
    const int head = c >> 5;
    const int d    = c & 31;
    const int bh   = b * kHeads + head;

    float o = 0.f, l = 0.f;
    for (int s = 0; s < ks; ++s) {
        const size_t pbase = ((size_t)s * (kB * kHeads) + bh) * kHW + hw;
        o += po[pbase * kHD + d];
        l += ls[pbase];
    }
    abh[(size_t)idx] = f2bf_bits(o / l + lepe[idx]);
}

// ---------------------------------------------------------------------------
// Kernel 5: output projection via bf16 MFMA.
// ---------------------------------------------------------------------------
__global__ __launch_bounds__(256) void out_mfma_kernel(
    const unsigned short* __restrict__ abh, const unsigned short* __restrict__ wt,
    const float* __restrict__ bo, float* __restrict__ out)
{
    const unsigned short* wz = wt + (size_t)3 * 65536;
    const int tid  = threadIdx.x;
    const int w    = tid >> 6;
    const int lane = tid & 63;
    const int l    = lane & 15;
    const int g    = lane >> 4;
    const int m0   = blockIdx.x * 64 + w * 16;
    const int nb   = blockIdx.y * 64;

    f32x4 acc[4] = {};
    const unsigned short* arow = abh + (size_t)(m0 + l) * 256;
    #pragma unroll
    for (int kc = 0; kc < 8; ++kc) {
        const bf16x8 a = *reinterpret_cast<const bf16x8*>(arow + kc * 32 + g * 8);
        #pragma unroll
        for (int j = 0; j < 4; ++j) {
            const bf16x8 b = *reinterpret_cast<const bf16x8*>(
                wz + (size_t)(nb + 16 * j + l) * 256 + kc * 32 + g * 8);
            acc[j] = __builtin_amdgcn_mfma_f32_16x16x32_bf16(a, b, acc[j], 0, 0, 0);
        }
    }

    #pragma unroll
    for (int j = 0; j < 4; ++j) {
        const int c = nb + 16 * j + l;
        const float bias = bo[c];
        #pragma unroll
        for (int r = 0; r < 4; ++r)
            out[(size_t)(m0 + 4 * g + r) * 256 + c] = acc[j][r] + bias;
    }
}

// ---------------------------------------------------------------------------
extern "C" void kernel_launch(void* const* d_in, const int* in_sizes, int n_in,
                              void* d_out, int out_size, void* d_ws, size_t ws_size,
                              hipStream_t stream)
{
    const float* x    = (const float*)d_in[0];
    const float* sinb = (const float*)d_in[1];
    const float* cosb = (const float*)d_in[2];
    const float* mask = (const float*)d_in[3];
    const float* Wq   = (const float*)d_in[4];
    const float* bq   = (const float*)d_in[5];
    const float* Wk   = (const float*)d_in[6];
    const float* bk   = (const float*)d_in[7];
    const float* Wv   = (const float*)d_in[8];
    const float* bv   = (const float*)d_in[9];
    const float* lw   = (const float*)d_in[10];
    const float* lb   = (const float*)d_in[11];
    const float* Wo   = (const float*)d_in[12];
    const float* bo   = (const float*)d_in[13];
    float* out = (float*)d_out;

    const size_t NT = (size_t)kB * kHeads * kHW * kHD;  // 2359296 per tensor
    const size_t fixed = NT * 4 * 2 + NT * 2 * 5 + 4 * 65536 * 2;

    int ks = 4;
    while (ks > 1) {
        const size_t need = fixed + (size_t)ks * (NT * 4 + (size_t)kB * kHeads * kHW * 4);
        if (need <= ws_size) break;
        ks >>= 1;
    }
    const int kspan = kHW / ks;

    char* base = (char*)d_ws;
    float* vb   = (float*)base;                      base += NT * 4;
    float* lepe = (float*)base;                      base += NT * 4;
    unsigned short* xb  = (unsigned short*)base;     base += NT * 2;
    unsigned short* abh = (unsigned short*)base;     base += NT * 2;
    unsigned short* qbh = (unsigned short*)base;     base += NT * 2;
    unsigned short* kbh = (unsigned short*)base;     base += NT * 2;
    unsigned short* vt  = (unsigned short*)base;     base += NT * 2;
    unsigned short* wt  = (unsigned short*)base;     base += (size_t)4 * 65536 * 2;
    float* po = (float*)base;                        base += (size_t)ks * NT * 4;
    float* ls = (float*)base;                        base += (size_t)ks * kB * kHeads * kHW * 4;

    prep_kernel<<<dim3(3328), 256, 0, stream>>>(x, Wq, Wk, Wv, Wo, xb, wt);
    qkv_mfma_kernel<<<dim3(144, 4, 3), 256, 0, stream>>>(
        xb, wt, bq, bk, bv, sinb, cosb, qbh, kbh, vt, vb);
    lepe_kernel<<<dim3(9216), 256, 0, stream>>>(vb, lw, lb, lepe);
    attn_mfma_kernel<<<dim3(72, 8, ks), 512, 81920, stream>>>(
        (const __hip_bfloat16*)qbh, (const __hip_bfloat16*)kbh,
        (const __hip_bfloat16*)vt, mask, po, ls, kspan);
    combine_kernel<<<dim3(9216), 256, 0, stream>>>(po, ls, lepe, abh, ks);
    out_mfma_kernel<<<dim3(144, 4), 256, 0, stream>>>(abh, wt, bo, out);
}